// Round 1
// baseline (1178.093 us; speedup 1.0000x reference)
//
#include <hip/hip_runtime.h>
#include <math.h>

#define F_IN 512
#define HC1 256   // HEADS*HID
#define HEADS 4
#define HID 64
#define NCLS 64
#define NEG_SLOPE 0.2f
#define EPS_DENOM 1e-16f

__device__ inline float wave_sum(float v) {
#pragma unroll
  for (int s = 32; s > 0; s >>= 1) v += __shfl_xor(v, s);
  return v;
}
__device__ inline float wave_max(float v) {
#pragma unroll
  for (int s = 32; s > 0; s >>= 1) v = fmaxf(v, __shfl_xor(v, s));
  return v;
}

// ---------------- CSR build ----------------

__global__ void hist_kernel(const int* __restrict__ dst, int E, int* __restrict__ cnt) {
  int i = blockIdx.x * blockDim.x + threadIdx.x;
  int stride = gridDim.x * blockDim.x;
  for (int e = i; e < E; e += stride) atomicAdd(&cnt[dst[e]], 1);
}

// single-block inclusive scan over cnt[i]+1 (the +1 is the self loop)
__global__ void scan_kernel(const int* __restrict__ cnt, int n,
                            int* __restrict__ rowoff, int* __restrict__ cursor) {
  __shared__ int sdata[1024];
  __shared__ int s_carry;
  int tid = threadIdx.x;
  if (tid == 0) { s_carry = 0; rowoff[0] = 0; }
  __syncthreads();
  for (int base = 0; base < n; base += 1024) {
    int carry = s_carry;
    int i = base + tid;
    int v = (i < n) ? (cnt[i] + 1) : 0;
    sdata[tid] = v;
    __syncthreads();
    for (int s = 1; s < 1024; s <<= 1) {
      int t = (tid >= s) ? sdata[tid - s] : 0;
      __syncthreads();
      sdata[tid] += t;
      __syncthreads();
    }
    int incl = sdata[tid] + carry;
    if (i < n) { rowoff[i + 1] = incl; cursor[i] = incl - v; }
    __syncthreads();
    if (tid == 1023) s_carry = incl;
    __syncthreads();
  }
}

__global__ void scatter_kernel(const int* __restrict__ src, const int* __restrict__ dst,
                               int E, int n, int* __restrict__ cursor, int* __restrict__ esrc) {
  int i = blockIdx.x * blockDim.x + threadIdx.x;
  int stride = gridDim.x * blockDim.x;
  for (int e = i; e < E + n; e += stride) {
    int s, d;
    if (e < E) { s = src[e]; d = dst[e]; } else { s = e - E; d = s; }
    int pos = atomicAdd(&cursor[d], 1);
    esrc[pos] = s;
  }
}

// ---------------- fp32 SGEMM (round-1 baseline; MFMA bf16 comes later) ----------------

template <int BM, int BN, int BK, int TM, int TN>
__global__ __launch_bounds__((BM / TM) * (BN / TN))
void sgemm_kernel(const float* __restrict__ A, const float* __restrict__ B,
                  float* __restrict__ C, int M, int Nn, int K) {
  constexpr int THREADS = (BM / TM) * (BN / TN);
  __shared__ float As[BK][BM + 1];
  __shared__ float Bs[BK][BN];
  const int tx = threadIdx.x % (BN / TN);
  const int ty = threadIdx.x / (BN / TN);
  const int row0 = blockIdx.y * BM;
  const int col0 = blockIdx.x * BN;
  float acc[TM][TN] = {};
  for (int k0 = 0; k0 < K; k0 += BK) {
    for (int i = threadIdx.x; i < BM * BK; i += THREADS) {
      int mm = i / BK, kk = i % BK;
      int gr = row0 + mm;
      As[kk][mm] = (gr < M) ? A[(size_t)gr * K + k0 + kk] : 0.f;
    }
    for (int i = threadIdx.x; i < BK * BN; i += THREADS) {
      int kk = i / BN, nn = i % BN;
      Bs[kk][nn] = B[(size_t)(k0 + kk) * Nn + col0 + nn];
    }
    __syncthreads();
#pragma unroll
    for (int kk = 0; kk < BK; ++kk) {
      float ra[TM], rb[TN];
#pragma unroll
      for (int i = 0; i < TM; ++i) ra[i] = As[kk][ty * TM + i];
#pragma unroll
      for (int j = 0; j < TN; ++j) rb[j] = Bs[kk][tx * TN + j];
#pragma unroll
      for (int i = 0; i < TM; ++i)
#pragma unroll
        for (int j = 0; j < TN; ++j) acc[i][j] += ra[i] * rb[j];
    }
    __syncthreads();
  }
#pragma unroll
  for (int i = 0; i < TM; ++i) {
    int gr = row0 + ty * TM + i;
    if (gr < M) {
#pragma unroll
      for (int j = 0; j < TN; ++j) C[(size_t)gr * Nn + col0 + tx * TN + j] = acc[i][j];
    }
  }
}

// ---------------- attention logits (per-node dot with a_src/a_dst) ----------------

__global__ void attn1_kernel(const float* __restrict__ h1,
                             const float* __restrict__ a_src, const float* __restrict__ a_dst,
                             float* __restrict__ als, float* __restrict__ ald, int n) {
  int w = threadIdx.x >> 6;
  int node = blockIdx.x * 4 + w;
  if (node >= n) return;
  int lane = threadIdx.x & 63;
#pragma unroll
  for (int h = 0; h < HEADS; ++h) {
    float v = h1[(size_t)node * HC1 + h * HID + lane];
    float ps = wave_sum(v * a_src[h * HID + lane]);
    float pd = wave_sum(v * a_dst[h * HID + lane]);
    if (lane == 0) { als[node * HEADS + h] = ps; ald[node * HEADS + h] = pd; }
  }
}

__global__ void attn2_kernel(const float* __restrict__ h2,
                             const float* __restrict__ a_src, const float* __restrict__ a_dst,
                             float* __restrict__ als, float* __restrict__ ald, int n) {
  int w = threadIdx.x >> 6;
  int node = blockIdx.x * 4 + w;
  if (node >= n) return;
  int lane = threadIdx.x & 63;
  float v = h2[(size_t)node * NCLS + lane];
  float ps = wave_sum(v * a_src[lane]);
  float pd = wave_sum(v * a_dst[lane]);
  if (lane == 0) { als[node] = ps; ald[node] = pd; }
}

// ---------------- aggregation: one wave per destination node ----------------

__global__ void agg1_kernel(const float* __restrict__ h1,
                            const float* __restrict__ als, const float* __restrict__ ald,
                            const int* __restrict__ rowoff, const int* __restrict__ esrc,
                            const float* __restrict__ b1, float* __restrict__ hact, int n) {
  int w = threadIdx.x >> 6;
  int node = blockIdx.x * 4 + w;
  if (node >= n) return;
  int lane = threadIdx.x & 63;
  int beg = rowoff[node], end = rowoff[node + 1];
  float aldn[HEADS];
#pragma unroll
  for (int h = 0; h < HEADS; ++h) aldn[h] = ald[node * HEADS + h];
  // pass A: segment max per head (lanes split edges)
  float m[HEADS] = {-1e30f, -1e30f, -1e30f, -1e30f};
  for (int e = beg + lane; e < end; e += 64) {
    int s = esrc[e];
#pragma unroll
    for (int h = 0; h < HEADS; ++h) {
      float v = als[s * HEADS + h] + aldn[h];
      v = v > 0.f ? v : NEG_SLOPE * v;
      m[h] = fmaxf(m[h], v);
    }
  }
#pragma unroll
  for (int h = 0; h < HEADS; ++h) m[h] = wave_max(m[h]);
  // pass B: weighted accumulate (lane = channel within head)
  float denom[HEADS] = {0.f, 0.f, 0.f, 0.f};
  float acc[HEADS] = {0.f, 0.f, 0.f, 0.f};
  for (int e = beg; e < end; ++e) {
    int s = esrc[e];
#pragma unroll
    for (int h = 0; h < HEADS; ++h) {
      float v = als[s * HEADS + h] + aldn[h];
      v = v > 0.f ? v : NEG_SLOPE * v;
      float wgt = expf(v - m[h]);
      denom[h] += wgt;
      acc[h] += wgt * h1[(size_t)s * HC1 + h * HID + lane];
    }
  }
#pragma unroll
  for (int h = 0; h < HEADS; ++h) {
    float o = acc[h] / (denom[h] + EPS_DENOM) + b1[h * HID + lane];
    o = o > 0.f ? o : expm1f(o);   // ELU
    hact[(size_t)node * HC1 + h * HID + lane] = o;
  }
}

__global__ void agg2_kernel(const float* __restrict__ h2,
                            const float* __restrict__ als, const float* __restrict__ ald,
                            const int* __restrict__ rowoff, const int* __restrict__ esrc,
                            const float* __restrict__ b2, float* __restrict__ out, int n) {
  int w = threadIdx.x >> 6;
  int node = blockIdx.x * 4 + w;
  if (node >= n) return;
  int lane = threadIdx.x & 63;
  int beg = rowoff[node], end = rowoff[node + 1];
  float aldn = ald[node];
  float m = -1e30f;
  for (int e = beg + lane; e < end; e += 64) {
    float v = als[esrc[e]] + aldn;
    v = v > 0.f ? v : NEG_SLOPE * v;
    m = fmaxf(m, v);
  }
  m = wave_max(m);
  float denom = 0.f, acc = 0.f;
  for (int e = beg; e < end; ++e) {
    int s = esrc[e];
    float v = als[s] + aldn;
    v = v > 0.f ? v : NEG_SLOPE * v;
    float wgt = expf(v - m);
    denom += wgt;
    acc += wgt * h2[(size_t)s * NCLS + lane];
  }
  float o = acc / (denom + EPS_DENOM) + b2[lane];
  // fused log_softmax over the 64 classes (== one wave)
  float mx = wave_max(o);
  float sm = wave_sum(expf(o - mx));
  out[(size_t)node * NCLS + lane] = o - mx - logf(sm);
}

// ---------------- launch ----------------

extern "C" void kernel_launch(void* const* d_in, const int* in_sizes, int n_in,
                              void* d_out, int out_size, void* d_ws, size_t ws_size,
                              hipStream_t stream) {
  const float* x      = (const float*)d_in[0];
  const int*   eidx   = (const int*)d_in[1];
  const float* W1     = (const float*)d_in[2];
  const float* a_src1 = (const float*)d_in[3];
  const float* a_dst1 = (const float*)d_in[4];
  const float* b1     = (const float*)d_in[5];
  const float* W2     = (const float*)d_in[6];
  const float* a_src2 = (const float*)d_in[7];
  const float* a_dst2 = (const float*)d_in[8];
  const float* b2     = (const float*)d_in[9];
  float* out = (float*)d_out;

  const int Nn = in_sizes[0] / F_IN;   // 50000
  const int E  = in_sizes[1] / 2;      // 800000
  const int* esrc_in = eidx;
  const int* edst_in = eidx + E;

  char* ws = (char*)d_ws;
  size_t off = 0;
  auto alloc = [&](size_t bytes) -> void* {
    void* p = ws + off;
    off += (bytes + 255) & ~(size_t)255;
    return p;
  };
  float* h1     = (float*)alloc((size_t)Nn * HC1 * sizeof(float));
  float* hact   = (float*)alloc((size_t)Nn * HC1 * sizeof(float));
  float* als1   = (float*)alloc((size_t)Nn * HEADS * sizeof(float));
  float* ald1   = (float*)alloc((size_t)Nn * HEADS * sizeof(float));
  float* als2   = (float*)alloc((size_t)Nn * sizeof(float));
  float* ald2   = (float*)alloc((size_t)Nn * sizeof(float));
  int*   cnt    = (int*)alloc((size_t)Nn * sizeof(int));
  int*   rowoff = (int*)alloc((size_t)(Nn + 1) * sizeof(int));
  int*   cursor = (int*)alloc((size_t)Nn * sizeof(int));
  int*   esrc   = (int*)alloc((size_t)(E + Nn) * sizeof(int));
  float* h2     = h1;  // h1 is dead after agg1 -> reuse for layer-2 features

  // CSR build (by destination), reused by both layers
  hipMemsetAsync(cnt, 0, (size_t)Nn * sizeof(int), stream);
  {
    int blocks = (E + 255) / 256;
    hist_kernel<<<blocks, 256, 0, stream>>>(edst_in, E, cnt);
  }
  scan_kernel<<<1, 1024, 0, stream>>>(cnt, Nn, rowoff, cursor);
  {
    int blocks = (E + Nn + 255) / 256;
    scatter_kernel<<<blocks, 256, 0, stream>>>(esrc_in, edst_in, E, Nn, cursor, esrc);
  }

  // layer 1
  {
    dim3 g(HC1 / 128, (Nn + 127) / 128);
    sgemm_kernel<128, 128, 16, 8, 8><<<g, 256, 0, stream>>>(x, W1, h1, Nn, HC1, F_IN);
  }
  {
    int blocks = (Nn + 3) / 4;
    attn1_kernel<<<blocks, 256, 0, stream>>>(h1, a_src1, a_dst1, als1, ald1, Nn);
    agg1_kernel<<<blocks, 256, 0, stream>>>(h1, als1, ald1, rowoff, esrc, b1, hact, Nn);
  }

  // layer 2
  {
    dim3 g(NCLS / 64, (Nn + 127) / 128);
    sgemm_kernel<128, 64, 16, 8, 4><<<g, 256, 0, stream>>>(hact, W2, h2, Nn, NCLS, HC1);
  }
  {
    int blocks = (Nn + 3) / 4;
    attn2_kernel<<<blocks, 256, 0, stream>>>(h2, a_src2, a_dst2, als2, ald2, Nn);
    agg2_kernel<<<blocks, 256, 0, stream>>>(h2, als2, ald2, rowoff, esrc, b2, out, Nn);
  }
}

// Round 2
// 535.196 us; speedup vs baseline: 2.2012x; 2.2012x over previous
//
#include <hip/hip_runtime.h>
#include <math.h>

#define F_IN 512
#define HC1 256   // HEADS*HID
#define HEADS 4
#define HID 64
#define NCLS 64
#define NEG_SLOPE 0.2f
#define EPS_DENOM 1e-16f

using short8 = __attribute__((ext_vector_type(8))) short;
using f32x4  = __attribute__((ext_vector_type(4))) float;

__device__ inline float wave_sum(float v) {
#pragma unroll
  for (int s = 32; s > 0; s >>= 1) v += __shfl_xor(v, s);
  return v;
}
__device__ inline float wave_max(float v) {
#pragma unroll
  for (int s = 32; s > 0; s >>= 1) v = fmaxf(v, __shfl_xor(v, s));
  return v;
}

__device__ inline unsigned short f2bf(float f) {
  unsigned int u = __float_as_uint(f);
  u = (u + 0x7FFF + ((u >> 16) & 1)) >> 16;   // RNE
  return (unsigned short)u;
}

__device__ inline void async_copy16(const void* g, void* l) {
  __builtin_amdgcn_global_load_lds((const __attribute__((address_space(1))) void*)g,
                                   (__attribute__((address_space(3))) void*)l, 16, 0, 0);
}

// ---------------- casts ----------------

__global__ void cast_bf16_kernel(const float* __restrict__ in, unsigned short* __restrict__ out,
                                 int n4) {
  int i = blockIdx.x * blockDim.x + threadIdx.x;
  if (i >= n4) return;
  float4 v = ((const float4*)in)[i];
  ushort4 o;
  o.x = f2bf(v.x); o.y = f2bf(v.y); o.z = f2bf(v.z); o.w = f2bf(v.w);
  ((ushort4*)out)[i] = o;
}

// WT[n][k] = bf16(W[k][n]);  output-linear indexing (coalesced write)
__global__ void castT_kernel(const float* __restrict__ W, unsigned short* __restrict__ WT,
                             int K, int Nn) {
  int id = blockIdx.x * blockDim.x + threadIdx.x;
  if (id >= K * Nn) return;
  int n = id / K, k = id % K;
  WT[id] = f2bf(W[(size_t)k * Nn + n]);
}

// ---------------- CSR build ----------------

__global__ void hist_kernel(const int* __restrict__ dst, int E, int* __restrict__ cnt) {
  int i = blockIdx.x * blockDim.x + threadIdx.x;
  int stride = gridDim.x * blockDim.x;
  for (int e = i; e < E; e += stride) atomicAdd(&cnt[dst[e]], 1);
}

__global__ void scan_kernel(const int* __restrict__ cnt, int n,
                            int* __restrict__ rowoff, int* __restrict__ cursor) {
  __shared__ int sdata[1024];
  __shared__ int s_carry;
  int tid = threadIdx.x;
  if (tid == 0) { s_carry = 0; rowoff[0] = 0; }
  __syncthreads();
  for (int base = 0; base < n; base += 1024) {
    int carry = s_carry;
    int i = base + tid;
    int v = (i < n) ? (cnt[i] + 1) : 0;
    sdata[tid] = v;
    __syncthreads();
    for (int s = 1; s < 1024; s <<= 1) {
      int t = (tid >= s) ? sdata[tid - s] : 0;
      __syncthreads();
      sdata[tid] += t;
      __syncthreads();
    }
    int incl = sdata[tid] + carry;
    if (i < n) { rowoff[i + 1] = incl; cursor[i] = incl - v; }
    __syncthreads();
    if (tid == 1023) s_carry = incl;
    __syncthreads();
  }
}

__global__ void scatter_kernel(const int* __restrict__ src, const int* __restrict__ dst,
                               int E, int n, int* __restrict__ cursor, int* __restrict__ esrc) {
  int i = blockIdx.x * blockDim.x + threadIdx.x;
  int stride = gridDim.x * blockDim.x;
  for (int e = i; e < E + n; e += stride) {
    int s, d;
    if (e < E) { s = src[e]; d = dst[e]; } else { s = e - E; d = s; }
    int pos = atomicAdd(&cursor[d], 1);
    esrc[pos] = s;
  }
}

// ---------------- bf16 MFMA GEMM (m97 structure: 128-row tile, BK=32, gload_lds w16) ----
// A [M][K] bf16 row-major, BT [N][K] bf16 (pre-transposed B), C [M][N] fp32.

template <int BN>
__global__ __launch_bounds__(256)
void mfma_gemm_kernel(const unsigned short* __restrict__ A,
                      const unsigned short* __restrict__ BT,
                      float* __restrict__ C, int M, int Nn, int K) {
  constexpr int BM = 128, BK = 32;
  constexpr int NACC = BN / 32;                 // N-fragments per wave (WN=2)
  __shared__ unsigned short Alds[BM * BK];      // [128][32]
  __shared__ unsigned short Blds[BN * BK];      // [BN][32]  (B^T tile)
  const int t = threadIdx.x;
  const int lane = t & 63;
  const int w = t >> 6;
  const int wr = (w >> 1) * 64;                 // wave row offset in tile
  const int wc = (w & 1) * (BN / 2);            // wave col offset in tile
  const int row0 = blockIdx.y * BM;
  const int col0 = blockIdx.x * BN;
  const int lrow = lane & 15;
  const int lk = (lane >> 4) * 8;

  f32x4 acc[4][NACC] = {};

  constexpr int AI = (BM * BK) / (256 * 8);     // 16B chunks per thread for A (=2)
  constexpr int BI = (BN * BK) / (256 * 8);     // for B (=2 or 1)

  for (int k0 = 0; k0 < K; k0 += BK) {
#pragma unroll
    for (int i = 0; i < AI; ++i) {
      int c = i * 256 + t;                      // 16B chunk index
      int ar = c >> 2;                          // tile row (32 bf16 = 4 chunks/row)
      int ak = (c & 3) * 8;
      int grow = row0 + ar; if (grow > M - 1) grow = M - 1;   // tail clamp
      const unsigned short* g = A + (size_t)grow * K + k0 + ak;
      unsigned short* l = Alds + (size_t)(i * 256 + w * 64) * 8;  // wave-uniform base
      async_copy16(g, l);
    }
#pragma unroll
    for (int i = 0; i < BI; ++i) {
      int c = i * 256 + t;
      int br = c >> 2;
      int bk = (c & 3) * 8;
      const unsigned short* g = BT + (size_t)(col0 + br) * K + k0 + bk;
      unsigned short* l = Blds + (size_t)(i * 256 + w * 64) * 8;
      async_copy16(g, l);
    }
    __syncthreads();
    short8 a[4], b[NACC];
#pragma unroll
    for (int m = 0; m < 4; ++m)
      a[m] = *(const short8*)&Alds[(wr + m * 16 + lrow) * BK + lk];
#pragma unroll
    for (int n = 0; n < NACC; ++n)
      b[n] = *(const short8*)&Blds[(wc + n * 16 + lrow) * BK + lk];
#pragma unroll
    for (int m = 0; m < 4; ++m)
#pragma unroll
      for (int n = 0; n < NACC; ++n)
        acc[m][n] = __builtin_amdgcn_mfma_f32_16x16x32_bf16(a[m], b[n], acc[m][n], 0, 0, 0);
    __syncthreads();
  }
  // C/D layout: col = lane&15, row = (lane>>4)*4 + j   [m89/m91 verified]
#pragma unroll
  for (int m = 0; m < 4; ++m) {
#pragma unroll
    for (int j = 0; j < 4; ++j) {
      int r = row0 + wr + m * 16 + (lane >> 4) * 4 + j;
      if (r < M) {
#pragma unroll
        for (int n = 0; n < NACC; ++n)
          C[(size_t)r * Nn + col0 + wc + n * 16 + lrow] = acc[m][n][j];
      }
    }
  }
}

// ---------------- attention logits ----------------

__global__ void attn1_kernel(const float* __restrict__ h1,
                             const float* __restrict__ a_src, const float* __restrict__ a_dst,
                             float* __restrict__ als, float* __restrict__ ald, int n) {
  int w = threadIdx.x >> 6;
  int node = blockIdx.x * 4 + w;
  if (node >= n) return;
  int lane = threadIdx.x & 63;
#pragma unroll
  for (int h = 0; h < HEADS; ++h) {
    float v = h1[(size_t)node * HC1 + h * HID + lane];
    float ps = wave_sum(v * a_src[h * HID + lane]);
    float pd = wave_sum(v * a_dst[h * HID + lane]);
    if (lane == 0) { als[node * HEADS + h] = ps; ald[node * HEADS + h] = pd; }
  }
}

__global__ void attn2_kernel(const float* __restrict__ h2,
                             const float* __restrict__ a_src, const float* __restrict__ a_dst,
                             float* __restrict__ als, float* __restrict__ ald, int n) {
  int w = threadIdx.x >> 6;
  int node = blockIdx.x * 4 + w;
  if (node >= n) return;
  int lane = threadIdx.x & 63;
  float v = h2[(size_t)node * NCLS + lane];
  float ps = wave_sum(v * a_src[lane]);
  float pd = wave_sum(v * a_dst[lane]);
  if (lane == 0) { als[node] = ps; ald[node] = pd; }
}

// ---------------- aggregation: one wave per destination node ----------------

__global__ void agg1_kernel(const float* __restrict__ h1,
                            const float* __restrict__ als, const float* __restrict__ ald,
                            const int* __restrict__ rowoff, const int* __restrict__ esrc,
                            const float* __restrict__ b1, unsigned short* __restrict__ hact,
                            int n) {
  int w = threadIdx.x >> 6;
  int node = blockIdx.x * 4 + w;
  if (node >= n) return;
  int lane = threadIdx.x & 63;
  int beg = rowoff[node], end = rowoff[node + 1];
  float aldn[HEADS];
#pragma unroll
  for (int h = 0; h < HEADS; ++h) aldn[h] = ald[node * HEADS + h];
  float m[HEADS] = {-1e30f, -1e30f, -1e30f, -1e30f};
  for (int e = beg + lane; e < end; e += 64) {
    int s = esrc[e];
#pragma unroll
    for (int h = 0; h < HEADS; ++h) {
      float v = als[s * HEADS + h] + aldn[h];
      v = v > 0.f ? v : NEG_SLOPE * v;
      m[h] = fmaxf(m[h], v);
    }
  }
#pragma unroll
  for (int h = 0; h < HEADS; ++h) m[h] = wave_max(m[h]);
  float denom[HEADS] = {0.f, 0.f, 0.f, 0.f};
  float acc[HEADS] = {0.f, 0.f, 0.f, 0.f};
  for (int e = beg; e < end; ++e) {
    int s = esrc[e];
#pragma unroll
    for (int h = 0; h < HEADS; ++h) {
      float v = als[s * HEADS + h] + aldn[h];
      v = v > 0.f ? v : NEG_SLOPE * v;
      float wgt = expf(v - m[h]);
      denom[h] += wgt;
      acc[h] += wgt * h1[(size_t)s * HC1 + h * HID + lane];
    }
  }
#pragma unroll
  for (int h = 0; h < HEADS; ++h) {
    float o = acc[h] / (denom[h] + EPS_DENOM) + b1[h * HID + lane];
    o = o > 0.f ? o : expm1f(o);   // ELU
    hact[(size_t)node * HC1 + h * HID + lane] = f2bf(o);
  }
}

__global__ void agg2_kernel(const float* __restrict__ h2,
                            const float* __restrict__ als, const float* __restrict__ ald,
                            const int* __restrict__ rowoff, const int* __restrict__ esrc,
                            const float* __restrict__ b2, float* __restrict__ out, int n) {
  int w = threadIdx.x >> 6;
  int node = blockIdx.x * 4 + w;
  if (node >= n) return;
  int lane = threadIdx.x & 63;
  int beg = rowoff[node], end = rowoff[node + 1];
  float aldn = ald[node];
  float m = -1e30f;
  for (int e = beg + lane; e < end; e += 64) {
    float v = als[esrc[e]] + aldn;
    v = v > 0.f ? v : NEG_SLOPE * v;
    m = fmaxf(m, v);
  }
  m = wave_max(m);
  float denom = 0.f, acc = 0.f;
  for (int e = beg; e < end; ++e) {
    int s = esrc[e];
    float v = als[s] + aldn;
    v = v > 0.f ? v : NEG_SLOPE * v;
    float wgt = expf(v - m);
    denom += wgt;
    acc += wgt * h2[(size_t)s * NCLS + lane];
  }
  float o = acc / (denom + EPS_DENOM) + b2[lane];
  float mx = wave_max(o);
  float sm = wave_sum(expf(o - mx));
  out[(size_t)node * NCLS + lane] = o - mx - logf(sm);
}

// ---------------- launch ----------------

extern "C" void kernel_launch(void* const* d_in, const int* in_sizes, int n_in,
                              void* d_out, int out_size, void* d_ws, size_t ws_size,
                              hipStream_t stream) {
  const float* x      = (const float*)d_in[0];
  const int*   eidx   = (const int*)d_in[1];
  const float* W1     = (const float*)d_in[2];
  const float* a_src1 = (const float*)d_in[3];
  const float* a_dst1 = (const float*)d_in[4];
  const float* b1     = (const float*)d_in[5];
  const float* W2     = (const float*)d_in[6];
  const float* a_src2 = (const float*)d_in[7];
  const float* a_dst2 = (const float*)d_in[8];
  const float* b2     = (const float*)d_in[9];
  float* out = (float*)d_out;

  const int Nn = in_sizes[0] / F_IN;   // 50000
  const int E  = in_sizes[1] / 2;      // 800000
  const int* esrc_in = eidx;
  const int* edst_in = eidx + E;

  char* ws = (char*)d_ws;
  size_t off = 0;
  auto alloc = [&](size_t bytes) -> void* {
    void* p = ws + off;
    off += (bytes + 255) & ~(size_t)255;
    return p;
  };
  float*          h1     = (float*)alloc((size_t)Nn * HC1 * sizeof(float));
  unsigned short* xbf    = (unsigned short*)alloc((size_t)Nn * F_IN * sizeof(short));
  unsigned short* hact   = (unsigned short*)alloc((size_t)Nn * HC1 * sizeof(short));
  unsigned short* W1T    = (unsigned short*)alloc((size_t)F_IN * HC1 * sizeof(short));
  unsigned short* W2T    = (unsigned short*)alloc((size_t)HC1 * NCLS * sizeof(short));
  float*          als1   = (float*)alloc((size_t)Nn * HEADS * sizeof(float));
  float*          ald1   = (float*)alloc((size_t)Nn * HEADS * sizeof(float));
  float*          als2   = (float*)alloc((size_t)Nn * sizeof(float));
  float*          ald2   = (float*)alloc((size_t)Nn * sizeof(float));
  int*            cnt    = (int*)alloc((size_t)Nn * sizeof(int));
  int*            rowoff = (int*)alloc((size_t)(Nn + 1) * sizeof(int));
  int*            cursor = (int*)alloc((size_t)Nn * sizeof(int));
  int*            esrc   = (int*)alloc((size_t)(E + Nn) * sizeof(int));
  float*          h2     = h1;  // h1 dead after agg1 -> reuse for layer-2 logits

  // casts (independent of CSR build)
  {
    int n4 = Nn * F_IN / 4;
    cast_bf16_kernel<<<(n4 + 255) / 256, 256, 0, stream>>>(x, xbf, n4);
    castT_kernel<<<(F_IN * HC1 + 255) / 256, 256, 0, stream>>>(W1, W1T, F_IN, HC1);
    castT_kernel<<<(HC1 * NCLS + 255) / 256, 256, 0, stream>>>(W2, W2T, HC1, NCLS);
  }

  // CSR build (by destination), reused by both layers
  hipMemsetAsync(cnt, 0, (size_t)Nn * sizeof(int), stream);
  hist_kernel<<<(E + 255) / 256, 256, 0, stream>>>(edst_in, E, cnt);
  scan_kernel<<<1, 1024, 0, stream>>>(cnt, Nn, rowoff, cursor);
  scatter_kernel<<<(E + Nn + 255) / 256, 256, 0, stream>>>(esrc_in, edst_in, E, Nn, cursor, esrc);

  // layer 1: h1 = x @ W1 (bf16 MFMA)
  {
    dim3 g(HC1 / 128, (Nn + 127) / 128);
    mfma_gemm_kernel<128><<<g, 256, 0, stream>>>(xbf, W1T, h1, Nn, HC1, F_IN);
  }
  {
    int blocks = (Nn + 3) / 4;
    attn1_kernel<<<blocks, 256, 0, stream>>>(h1, a_src1, a_dst1, als1, ald1, Nn);
    agg1_kernel<<<blocks, 256, 0, stream>>>(h1, als1, ald1, rowoff, esrc, b1, hact, Nn);
  }

  // layer 2: h2 = hact @ W2 (bf16 MFMA)
  {
    dim3 g(NCLS / 64, (Nn + 127) / 128);
    mfma_gemm_kernel<64><<<g, 256, 0, stream>>>(hact, W2T, h2, Nn, NCLS, HC1);
  }
  {
    int blocks = (Nn + 3) / 4;
    attn2_kernel<<<blocks, 256, 0, stream>>>(h2, a_src2, a_dst2, als2, ald2, Nn);
    agg2_kernel<<<blocks, 256, 0, stream>>>(h2, als2, ald2, rowoff, esrc, b2, out, Nn);
  }
}

// Round 3
// 362.043 us; speedup vs baseline: 3.2540x; 1.4783x over previous
//
#include <hip/hip_runtime.h>
#include <math.h>

#define F_IN 512
#define HC1 256   // HEADS*HID
#define HEADS 4
#define HID 64
#define NCLS 64
#define NEG_SLOPE 0.2f
#define EPS_DENOM 1e-16f

using short8 = __attribute__((ext_vector_type(8))) short;
using f32x4  = __attribute__((ext_vector_type(4))) float;

__device__ inline float wave_sum(float v) {
#pragma unroll
  for (int s = 32; s > 0; s >>= 1) v += __shfl_xor(v, s);
  return v;
}
__device__ inline float wave_max(float v) {
#pragma unroll
  for (int s = 32; s > 0; s >>= 1) v = fmaxf(v, __shfl_xor(v, s));
  return v;
}

__device__ inline unsigned short f2bf(float f) {
  unsigned int u = __float_as_uint(f);
  u = (u + 0x7FFF + ((u >> 16) & 1)) >> 16;   // RNE
  return (unsigned short)u;
}
__device__ inline float bflo(unsigned int u) { return __uint_as_float(u << 16); }
__device__ inline float bfhi(unsigned int u) { return __uint_as_float(u & 0xFFFF0000u); }

__device__ inline float rdlane_f(float v, int j) {
  return __int_as_float(__builtin_amdgcn_readlane(__float_as_int(v), j));
}

__device__ inline void async_copy16(const void* g, void* l) {
  __builtin_amdgcn_global_load_lds((const __attribute__((address_space(1))) void*)g,
                                   (__attribute__((address_space(3))) void*)l, 16, 0, 0);
}

// ---------------- casts ----------------

__global__ void cast_bf16_kernel(const float* __restrict__ in, unsigned short* __restrict__ out,
                                 int n4) {
  int i = blockIdx.x * blockDim.x + threadIdx.x;
  if (i >= n4) return;
  float4 v = ((const float4*)in)[i];
  ushort4 o;
  o.x = f2bf(v.x); o.y = f2bf(v.y); o.z = f2bf(v.z); o.w = f2bf(v.w);
  ((ushort4*)out)[i] = o;
}

// WT[n][k] = bf16(W[k][n])
__global__ void castT_kernel(const float* __restrict__ W, unsigned short* __restrict__ WT,
                             int K, int Nn) {
  int id = blockIdx.x * blockDim.x + threadIdx.x;
  if (id >= K * Nn) return;
  int n = id / K, k = id % K;
  WT[id] = f2bf(W[(size_t)k * Nn + n]);
}

// ---------------- CSR build ----------------

__global__ void hist_kernel(const int* __restrict__ dst, int E, int* __restrict__ cnt) {
  int i = blockIdx.x * blockDim.x + threadIdx.x;
  int stride = gridDim.x * blockDim.x;
  for (int e = i; e < E; e += stride) atomicAdd(&cnt[dst[e]], 1);
}

// single-block scan over cnt[i]+1 (the +1 is the self loop), shfl-based
__global__ void scan_kernel(const int* __restrict__ cnt, int n,
                            int* __restrict__ rowoff, int* __restrict__ cursor) {
  __shared__ int wpart[16];
  __shared__ int s_carry;
  int tid = threadIdx.x;
  int lane = tid & 63, wid = tid >> 6;
  if (tid == 0) { s_carry = 0; rowoff[0] = 0; }
  __syncthreads();
  for (int base = 0; base < n; base += 1024) {
    int i = base + tid;
    int v = (i < n) ? (cnt[i] + 1) : 0;
    int x = v;
#pragma unroll
    for (int s = 1; s < 64; s <<= 1) {
      int t = __shfl_up(x, s);
      if (lane >= s) x += t;
    }
    if (lane == 63) wpart[wid] = x;
    __syncthreads();
    if (wid == 0) {
      int p = (lane < 16) ? wpart[lane] : 0;
#pragma unroll
      for (int s = 1; s < 16; s <<= 1) {
        int t = __shfl_up(p, s);
        if (lane >= s) p += t;
      }
      if (lane < 16) wpart[lane] = p;
    }
    __syncthreads();
    int woff = (wid == 0) ? 0 : wpart[wid - 1];
    int incl = x + woff + s_carry;
    if (i < n) { rowoff[i + 1] = incl; cursor[i] = incl - v; }
    __syncthreads();
    if (tid == 1023) s_carry = incl;
    __syncthreads();
  }
}

__global__ void scatter_kernel(const int* __restrict__ src, const int* __restrict__ dst,
                               int E, int n, int* __restrict__ cursor, int* __restrict__ esrc) {
  int i = blockIdx.x * blockDim.x + threadIdx.x;
  int stride = gridDim.x * blockDim.x;
  for (int e = i; e < E + n; e += stride) {
    int s, d;
    if (e < E) { s = src[e]; d = dst[e]; } else { s = e - E; d = s; }
    int pos = atomicAdd(&cursor[d], 1);
    esrc[pos] = s;
  }
}

// ---------------- bf16 MFMA GEMM, bf16 output ----------------
// A [M][K] bf16, BT [N][K] bf16 (pre-transposed B), Cb [M][N] bf16.

template <int BN>
__global__ __launch_bounds__(256)
void mfma_gemm_kernel(const unsigned short* __restrict__ A,
                      const unsigned short* __restrict__ BT,
                      unsigned short* __restrict__ Cb, int M, int Nn, int K) {
  constexpr int BM = 128, BK = 32;
  constexpr int NACC = BN / 32;
  __shared__ unsigned short Alds[BM * BK];
  __shared__ unsigned short Blds[BN * BK];
  const int t = threadIdx.x;
  const int lane = t & 63;
  const int w = t >> 6;
  const int wr = (w >> 1) * 64;
  const int wc = (w & 1) * (BN / 2);
  const int row0 = blockIdx.y * BM;
  const int col0 = blockIdx.x * BN;
  const int lrow = lane & 15;
  const int lk = (lane >> 4) * 8;

  f32x4 acc[4][NACC] = {};
  constexpr int AI = (BM * BK) / (256 * 8);
  constexpr int BI = (BN * BK) / (256 * 8);

  for (int k0 = 0; k0 < K; k0 += BK) {
#pragma unroll
    for (int i = 0; i < AI; ++i) {
      int c = i * 256 + t;
      int ar = c >> 2;
      int ak = (c & 3) * 8;
      int grow = row0 + ar; if (grow > M - 1) grow = M - 1;
      const unsigned short* g = A + (size_t)grow * K + k0 + ak;
      unsigned short* l = Alds + (size_t)(i * 256 + w * 64) * 8;
      async_copy16(g, l);
    }
#pragma unroll
    for (int i = 0; i < BI; ++i) {
      int c = i * 256 + t;
      int br = c >> 2;
      int bk = (c & 3) * 8;
      const unsigned short* g = BT + (size_t)(col0 + br) * K + k0 + bk;
      unsigned short* l = Blds + (size_t)(i * 256 + w * 64) * 8;
      async_copy16(g, l);
    }
    __syncthreads();
    short8 a[4], b[NACC];
#pragma unroll
    for (int m = 0; m < 4; ++m)
      a[m] = *(const short8*)&Alds[(wr + m * 16 + lrow) * BK + lk];
#pragma unroll
    for (int n = 0; n < NACC; ++n)
      b[n] = *(const short8*)&Blds[(wc + n * 16 + lrow) * BK + lk];
#pragma unroll
    for (int m = 0; m < 4; ++m)
#pragma unroll
      for (int n = 0; n < NACC; ++n)
        acc[m][n] = __builtin_amdgcn_mfma_f32_16x16x32_bf16(a[m], b[n], acc[m][n], 0, 0, 0);
    __syncthreads();
  }
#pragma unroll
  for (int m = 0; m < 4; ++m) {
#pragma unroll
    for (int j = 0; j < 4; ++j) {
      int r = row0 + wr + m * 16 + (lane >> 4) * 4 + j;
      if (r < M) {
#pragma unroll
        for (int n = 0; n < NACC; ++n)
          Cb[(size_t)r * Nn + col0 + wc + n * 16 + lrow] = f2bf(acc[m][n][j]);
      }
    }
  }
}

// ---------------- attention logits (bf16 features) ----------------

__global__ void attn1_kernel(const unsigned short* __restrict__ h1b,
                             const float* __restrict__ a_src, const float* __restrict__ a_dst,
                             float* __restrict__ als, float* __restrict__ ald, int n) {
  int w = threadIdx.x >> 6;
  int node = blockIdx.x * 4 + w;
  if (node >= n) return;
  int lane = threadIdx.x & 63;
  uint2 d = *(const uint2*)&h1b[(size_t)node * HC1 + lane * 4];
  float f0 = bflo(d.x), f1 = bfhi(d.x), f2 = bflo(d.y), f3 = bfhi(d.y);
  float4 as_ = ((const float4*)a_src)[lane];
  float4 ad_ = ((const float4*)a_dst)[lane];
  float ps = f0 * as_.x + f1 * as_.y + f2 * as_.z + f3 * as_.w;
  float pd = f0 * ad_.x + f1 * ad_.y + f2 * ad_.z + f3 * ad_.w;
#pragma unroll
  for (int s = 1; s < 16; s <<= 1) {
    ps += __shfl_xor(ps, s);
    pd += __shfl_xor(pd, s);
  }
  if ((lane & 15) == 0) {
    als[node * HEADS + (lane >> 4)] = ps;
    ald[node * HEADS + (lane >> 4)] = pd;
  }
}

__global__ void attn2_kernel(const unsigned short* __restrict__ h2b,
                             const float* __restrict__ a_src, const float* __restrict__ a_dst,
                             float* __restrict__ als, float* __restrict__ ald, int n) {
  int w = threadIdx.x >> 6;
  int node = blockIdx.x * 4 + w;
  if (node >= n) return;
  int lane = threadIdx.x & 63;
  float v = __uint_as_float(((unsigned int)h2b[(size_t)node * NCLS + lane]) << 16);
  float ps = wave_sum(v * a_src[lane]);
  float pd = wave_sum(v * a_dst[lane]);
  if (lane == 0) { als[node] = ps; ald[node] = pd; }
}

// ---------------- aggregation ----------------
// One wave per node. Per 64-edge chunk: lane-parallel exp-weight computation,
// then serial gather loop with v_readlane broadcast (scalar addr, SGPR weights).
// No segment max: alpha = exp(e)/sum(exp(e)) is exact without it (|e| <~ 13).

__global__ void agg1_kernel(const unsigned short* __restrict__ h1b,
                            const float4* __restrict__ als1, const float4* __restrict__ ald1,
                            const int* __restrict__ rowoff, const int* __restrict__ esrc,
                            const float* __restrict__ b1, unsigned short* __restrict__ hact,
                            int n) {
  int w = threadIdx.x >> 6;
  int node = blockIdx.x * 4 + w;
  if (node >= n) return;
  int lane = threadIdx.x & 63;
  int beg = rowoff[node], end = rowoff[node + 1];
  float4 aldn = ald1[node];
  int hsel = lane >> 4;           // head of channels lane*4 .. lane*4+3
  float4 acc = {0.f, 0.f, 0.f, 0.f};
  float4 dl  = {0.f, 0.f, 0.f, 0.f};
  for (int base = beg; base < end; base += 64) {
    int cnt = min(64, end - base);
    int e = base + lane;
    float w0 = 0.f, w1 = 0.f, w2 = 0.f, w3 = 0.f;
    int s = 0;
    if (e < end) {
      s = esrc[e];
      float4 av = als1[s];
      float v;
      v = av.x + aldn.x; v = fmaxf(v, NEG_SLOPE * v); w0 = __expf(v);
      v = av.y + aldn.y; v = fmaxf(v, NEG_SLOPE * v); w1 = __expf(v);
      v = av.z + aldn.z; v = fmaxf(v, NEG_SLOPE * v); w2 = __expf(v);
      v = av.w + aldn.w; v = fmaxf(v, NEG_SLOPE * v); w3 = __expf(v);
      dl.x += w0; dl.y += w1; dl.z += w2; dl.w += w3;
    }
    for (int j = 0; j < cnt; ++j) {
      int ss = __builtin_amdgcn_readlane(s, j);
      float q0 = rdlane_f(w0, j), q1 = rdlane_f(w1, j);
      float q2 = rdlane_f(w2, j), q3 = rdlane_f(w3, j);
      float wj = hsel < 2 ? (hsel == 0 ? q0 : q1) : (hsel == 2 ? q2 : q3);
      uint2 d = *(const uint2*)&h1b[(size_t)ss * HC1 + lane * 4];
      acc.x += wj * bflo(d.x);
      acc.y += wj * bfhi(d.x);
      acc.z += wj * bflo(d.y);
      acc.w += wj * bfhi(d.y);
    }
  }
  float d0 = wave_sum(dl.x), d1 = wave_sum(dl.y);
  float d2 = wave_sum(dl.z), d3 = wave_sum(dl.w);
  float den = hsel < 2 ? (hsel == 0 ? d0 : d1) : (hsel == 2 ? d2 : d3);
  float rden = 1.f / (den + EPS_DENOM);
  float4 bv = ((const float4*)b1)[lane];
  float o0 = acc.x * rden + bv.x;
  float o1 = acc.y * rden + bv.y;
  float o2 = acc.z * rden + bv.z;
  float o3 = acc.w * rden + bv.w;
  o0 = o0 > 0.f ? o0 : __expf(o0) - 1.f;   // ELU
  o1 = o1 > 0.f ? o1 : __expf(o1) - 1.f;
  o2 = o2 > 0.f ? o2 : __expf(o2) - 1.f;
  o3 = o3 > 0.f ? o3 : __expf(o3) - 1.f;
  ushort4 ov = {f2bf(o0), f2bf(o1), f2bf(o2), f2bf(o3)};
  *(ushort4*)&hact[(size_t)node * HC1 + lane * 4] = ov;
}

__global__ void agg2_kernel(const unsigned short* __restrict__ h2b,
                            const float* __restrict__ als2, const float* __restrict__ ald2,
                            const int* __restrict__ rowoff, const int* __restrict__ esrc,
                            const float* __restrict__ b2, float* __restrict__ out, int n) {
  int w = threadIdx.x >> 6;
  int node = blockIdx.x * 4 + w;
  if (node >= n) return;
  int lane = threadIdx.x & 63;
  int beg = rowoff[node], end = rowoff[node + 1];
  float aldn = ald2[node];
  float acc = 0.f, dl = 0.f;
  for (int base = beg; base < end; base += 64) {
    int cnt = min(64, end - base);
    int e = base + lane;
    float wl = 0.f;
    int s = 0;
    if (e < end) {
      s = esrc[e];
      float v = als2[s] + aldn;
      v = fmaxf(v, NEG_SLOPE * v);
      wl = __expf(v);
      dl += wl;
    }
    for (int j = 0; j < cnt; ++j) {
      int ss = __builtin_amdgcn_readlane(s, j);
      float wj = rdlane_f(wl, j);
      float f = __uint_as_float(((unsigned int)h2b[(size_t)ss * NCLS + lane]) << 16);
      acc += wj * f;
    }
  }
  float den = wave_sum(dl);
  float o = acc / (den + EPS_DENOM) + b2[lane];
  float mx = wave_max(o);
  float sm = wave_sum(__expf(o - mx));
  out[(size_t)node * NCLS + lane] = o - mx - __logf(sm);
}

// ---------------- launch ----------------

extern "C" void kernel_launch(void* const* d_in, const int* in_sizes, int n_in,
                              void* d_out, int out_size, void* d_ws, size_t ws_size,
                              hipStream_t stream) {
  const float* x      = (const float*)d_in[0];
  const int*   eidx   = (const int*)d_in[1];
  const float* W1     = (const float*)d_in[2];
  const float* a_src1 = (const float*)d_in[3];
  const float* a_dst1 = (const float*)d_in[4];
  const float* b1     = (const float*)d_in[5];
  const float* W2     = (const float*)d_in[6];
  const float* a_src2 = (const float*)d_in[7];
  const float* a_dst2 = (const float*)d_in[8];
  const float* b2     = (const float*)d_in[9];
  float* out = (float*)d_out;

  const int Nn = in_sizes[0] / F_IN;   // 50000
  const int E  = in_sizes[1] / 2;      // 800000
  const int* esrc_in = eidx;
  const int* edst_in = eidx + E;

  char* ws = (char*)d_ws;
  size_t off = 0;
  auto alloc = [&](size_t bytes) -> void* {
    void* p = ws + off;
    off += (bytes + 255) & ~(size_t)255;
    return p;
  };
  unsigned short* xbf    = (unsigned short*)alloc((size_t)Nn * F_IN * sizeof(short));
  unsigned short* h1b    = (unsigned short*)alloc((size_t)Nn * HC1 * sizeof(short));
  unsigned short* hact   = (unsigned short*)alloc((size_t)Nn * HC1 * sizeof(short));
  unsigned short* h2b    = (unsigned short*)alloc((size_t)Nn * NCLS * sizeof(short));
  unsigned short* W1T    = (unsigned short*)alloc((size_t)F_IN * HC1 * sizeof(short));
  unsigned short* W2T    = (unsigned short*)alloc((size_t)HC1 * NCLS * sizeof(short));
  float*          als1   = (float*)alloc((size_t)Nn * HEADS * sizeof(float));
  float*          ald1   = (float*)alloc((size_t)Nn * HEADS * sizeof(float));
  float*          als2   = (float*)alloc((size_t)Nn * sizeof(float));
  float*          ald2   = (float*)alloc((size_t)Nn * sizeof(float));
  int*            cnt    = (int*)alloc((size_t)Nn * sizeof(int));
  int*            rowoff = (int*)alloc((size_t)(Nn + 1) * sizeof(int));
  int*            cursor = (int*)alloc((size_t)Nn * sizeof(int));
  int*            esrc   = (int*)alloc((size_t)(E + Nn) * sizeof(int));

  // casts
  {
    int n4 = Nn * F_IN / 4;
    cast_bf16_kernel<<<(n4 + 255) / 256, 256, 0, stream>>>(x, xbf, n4);
    castT_kernel<<<(F_IN * HC1 + 255) / 256, 256, 0, stream>>>(W1, W1T, F_IN, HC1);
    castT_kernel<<<(HC1 * NCLS + 255) / 256, 256, 0, stream>>>(W2, W2T, HC1, NCLS);
  }

  // CSR build (by destination), reused by both layers
  hipMemsetAsync(cnt, 0, (size_t)Nn * sizeof(int), stream);
  hist_kernel<<<(E + 255) / 256, 256, 0, stream>>>(edst_in, E, cnt);
  scan_kernel<<<1, 1024, 0, stream>>>(cnt, Nn, rowoff, cursor);
  scatter_kernel<<<(E + Nn + 255) / 256, 256, 0, stream>>>(esrc_in, edst_in, E, Nn, cursor, esrc);

  // layer 1
  {
    dim3 g(HC1 / 128, (Nn + 127) / 128);
    mfma_gemm_kernel<128><<<g, 256, 0, stream>>>(xbf, W1T, h1b, Nn, HC1, F_IN);
  }
  {
    int blocks = (Nn + 3) / 4;
    attn1_kernel<<<blocks, 256, 0, stream>>>(h1b, a_src1, a_dst1, als1, ald1, Nn);
    agg1_kernel<<<blocks, 256, 0, stream>>>(h1b, (const float4*)als1, (const float4*)ald1,
                                            rowoff, esrc, b1, hact, Nn);
  }

  // layer 2
  {
    dim3 g(NCLS / 64, (Nn + 127) / 128);
    mfma_gemm_kernel<64><<<g, 256, 0, stream>>>(hact, W2T, h2b, Nn, NCLS, HC1);
  }
  {
    int blocks = (Nn + 3) / 4;
    attn2_kernel<<<blocks, 256, 0, stream>>>(h2b, a_src2, a_dst2, als2, ald2, Nn);
    agg2_kernel<<<blocks, 256, 0, stream>>>(h2b, als2, ald2, rowoff, esrc, b2, out, Nn);
  }
}

// Round 4
// 286.173 us; speedup vs baseline: 4.1167x; 1.2651x over previous
//
#include <hip/hip_runtime.h>
#include <math.h>

#define F_IN 512
#define HC1 256   // HEADS*HID
#define HEADS 4
#define HID 64
#define NCLS 64
#define NEG_SLOPE 0.2f
#define EPS_DENOM 1e-16f

using short8 = __attribute__((ext_vector_type(8))) short;
using f32x4  = __attribute__((ext_vector_type(4))) float;

__device__ inline float wave_sum(float v) {
#pragma unroll
  for (int s = 32; s > 0; s >>= 1) v += __shfl_xor(v, s);
  return v;
}
__device__ inline float wave_max(float v) {
#pragma unroll
  for (int s = 32; s > 0; s >>= 1) v = fmaxf(v, __shfl_xor(v, s));
  return v;
}

__device__ inline unsigned short f2bf(float f) {
  unsigned int u = __float_as_uint(f);
  u = (u + 0x7FFF + ((u >> 16) & 1)) >> 16;   // RNE
  return (unsigned short)u;
}
__device__ inline float bflo(unsigned int u) { return __uint_as_float(u << 16); }
__device__ inline float bfhi(unsigned int u) { return __uint_as_float(u & 0xFFFF0000u); }

__device__ inline unsigned int cvtpk_bf16(float lo, float hi) {
  unsigned int r;
  asm("v_cvt_pk_bf16_f32 %0, %1, %2" : "=v"(r) : "v"(lo), "v"(hi));
  return r;
}

__device__ inline void async_copy16(const void* g, void* l) {
  __builtin_amdgcn_global_load_lds((const __attribute__((address_space(1))) void*)g,
                                   (__attribute__((address_space(3))) void*)l, 16, 0, 0);
}

// ---------------- weight transpose-cast (small) ----------------
// WT[n][k] = bf16(W[k][n])
__global__ void castT_kernel(const float* __restrict__ W, unsigned short* __restrict__ WT,
                             int K, int Nn) {
  int id = blockIdx.x * blockDim.x + threadIdx.x;
  if (id >= K * Nn) return;
  int n = id / K, k = id % K;
  WT[id] = f2bf(W[(size_t)k * Nn + n]);
}

// ---------------- CSR build ----------------

__global__ void hist_kernel(const int* __restrict__ dst, int E, int* __restrict__ cnt) {
  int i = blockIdx.x * blockDim.x + threadIdx.x;
  int stride = gridDim.x * blockDim.x;
  for (int e = i; e < E; e += stride) atomicAdd(&cnt[dst[e]], 1);
}

// parallel scan, 3 kernels: per-block scan -> partials scan (1 wave) -> add offsets
__global__ void scan_blocks_kernel(const int* __restrict__ cnt, int n,
                                   int* __restrict__ rowoff, int* __restrict__ cursor,
                                   int* __restrict__ bsum) {
  __shared__ int wpart[16];
  int b = blockIdx.x, tid = threadIdx.x;
  int i = b * 1024 + tid;
  int lane = tid & 63, wid = tid >> 6;
  int v = (i < n) ? (cnt[i] + 1) : 0;   // +1 = self loop
  int x = v;
#pragma unroll
  for (int s = 1; s < 64; s <<= 1) {
    int t = __shfl_up(x, s);
    if (lane >= s) x += t;
  }
  if (lane == 63) wpart[wid] = x;
  __syncthreads();
  if (wid == 0) {
    int p = (lane < 16) ? wpart[lane] : 0;
#pragma unroll
    for (int s = 1; s < 16; s <<= 1) {
      int t = __shfl_up(p, s);
      if (lane >= s) p += t;
    }
    if (lane < 16) wpart[lane] = p;
  }
  __syncthreads();
  int incl = x + (wid ? wpart[wid - 1] : 0);
  if (i < n) { rowoff[i + 1] = incl; cursor[i] = incl - v; }
  if (tid == 1023) bsum[b] = incl;
  if (b == 0 && tid == 0) rowoff[0] = 0;
}

__global__ void scan_partials_kernel(int* __restrict__ bsum, int nb) {
  int lane = threadIdx.x;   // 64 threads, nb <= 64
  int v = (lane < nb) ? bsum[lane] : 0;
  int x = v;
#pragma unroll
  for (int s = 1; s < 64; s <<= 1) {
    int t = __shfl_up(x, s);
    if (lane >= s) x += t;
  }
  if (lane < nb) bsum[lane] = x - v;   // exclusive
}

__global__ void scan_add_kernel(int n, int* __restrict__ rowoff, int* __restrict__ cursor,
                                const int* __restrict__ bsum) {
  int i = blockIdx.x * 1024 + threadIdx.x;
  int off = bsum[blockIdx.x];
  if (i < n) { rowoff[i + 1] += off; cursor[i] += off; }
}

__global__ void scatter_kernel(const int* __restrict__ src, const int* __restrict__ dst,
                               int E, int n, int* __restrict__ cursor, int* __restrict__ esrc) {
  int i = blockIdx.x * blockDim.x + threadIdx.x;
  int stride = gridDim.x * blockDim.x;
  for (int e = i; e < E + n; e += stride) {
    int s, d;
    if (e < E) { s = src[e]; d = dst[e]; } else { s = e - E; d = s; }
    int pos = atomicAdd(&cursor[d], 1);
    esrc[pos] = s;
  }
}

// ---------------- GEMM1: fused fp32->bf16 A-staging, bf16 MFMA ----------------
// A = x fp32 [M][512], BT = W1T bf16 [256][512], Cb bf16 [M][256].

__global__ __launch_bounds__(256)
void gemm1_fused_kernel(const float* __restrict__ A, const unsigned short* __restrict__ BT,
                        unsigned short* __restrict__ Cb, int M) {
  constexpr int BM = 128, BN = 128, BK = 32, K = F_IN, Nn = HC1;
  __shared__ unsigned short Alds[BM * BK];
  __shared__ unsigned short Blds[BN * BK];
  const int t = threadIdx.x;
  const int lane = t & 63;
  const int w = t >> 6;
  const int wr = (w >> 1) * 64;
  const int wc = (w & 1) * 64;
  const int row0 = blockIdx.y * BM;
  const int col0 = blockIdx.x * BN;
  const int lrow = lane & 15;
  const int lk = (lane >> 4) * 8;

  f32x4 acc[4][4] = {};
  // A-stage map: thread -> (row = t>>1, k-half = (t&1)*16), 16 floats -> 16 bf16
  const int ar = t >> 1;
  const int kh = (t & 1) * 16;
  int grow = row0 + ar; if (grow > M - 1) grow = M - 1;
  const float* arow = A + (size_t)grow * K + kh;

  for (int k0 = 0; k0 < K; k0 += BK) {
    // B: async 16B copies (2 per thread)
#pragma unroll
    for (int i = 0; i < 2; ++i) {
      int c = i * 256 + t;
      int br = c >> 2;
      int bk = (c & 3) * 8;
      const unsigned short* g = BT + (size_t)(col0 + br) * K + k0 + bk;
      unsigned short* l = Blds + (size_t)(i * 256 + w * 64) * 8;
      async_copy16(g, l);
    }
    // A: reg-stage fp32 -> cvt_pk bf16 -> LDS
    const float4* gp = (const float4*)(arow + k0);
    float4 f0 = gp[0], f1 = gp[1], f2 = gp[2], f3 = gp[3];
    uint4 u0, u1;
    u0.x = cvtpk_bf16(f0.x, f0.y); u0.y = cvtpk_bf16(f0.z, f0.w);
    u0.z = cvtpk_bf16(f1.x, f1.y); u0.w = cvtpk_bf16(f1.z, f1.w);
    u1.x = cvtpk_bf16(f2.x, f2.y); u1.y = cvtpk_bf16(f2.z, f2.w);
    u1.z = cvtpk_bf16(f3.x, f3.y); u1.w = cvtpk_bf16(f3.z, f3.w);
    uint4* dstp = (uint4*)&Alds[ar * BK + kh];
    dstp[0] = u0; dstp[1] = u1;
    __syncthreads();
    short8 a[4], b[4];
#pragma unroll
    for (int m = 0; m < 4; ++m)
      a[m] = *(const short8*)&Alds[(wr + m * 16 + lrow) * BK + lk];
#pragma unroll
    for (int n = 0; n < 4; ++n)
      b[n] = *(const short8*)&Blds[(wc + n * 16 + lrow) * BK + lk];
#pragma unroll
    for (int m = 0; m < 4; ++m)
#pragma unroll
      for (int n = 0; n < 4; ++n)
        acc[m][n] = __builtin_amdgcn_mfma_f32_16x16x32_bf16(a[m], b[n], acc[m][n], 0, 0, 0);
    __syncthreads();
  }
#pragma unroll
  for (int m = 0; m < 4; ++m) {
#pragma unroll
    for (int j = 0; j < 4; ++j) {
      int r = row0 + wr + m * 16 + (lane >> 4) * 4 + j;
      if (r < M) {
#pragma unroll
        for (int n = 0; n < 4; ++n)
          Cb[(size_t)r * Nn + col0 + wc + n * 16 + lrow] = f2bf(acc[m][n][j]);
      }
    }
  }
}

// ---------------- GEMM2: bf16 A (m97-structure) ----------------

template <int BN>
__global__ __launch_bounds__(256)
void mfma_gemm_kernel(const unsigned short* __restrict__ A,
                      const unsigned short* __restrict__ BT,
                      unsigned short* __restrict__ Cb, int M, int Nn, int K) {
  constexpr int BM = 128, BK = 32;
  constexpr int NACC = BN / 32;
  __shared__ unsigned short Alds[BM * BK];
  __shared__ unsigned short Blds[BN * BK];
  const int t = threadIdx.x;
  const int lane = t & 63;
  const int w = t >> 6;
  const int wr = (w >> 1) * 64;
  const int wc = (w & 1) * (BN / 2);
  const int row0 = blockIdx.y * BM;
  const int col0 = blockIdx.x * BN;
  const int lrow = lane & 15;
  const int lk = (lane >> 4) * 8;

  f32x4 acc[4][NACC] = {};
  constexpr int AI = (BM * BK) / (256 * 8);
  constexpr int BI = (BN * BK) / (256 * 8);

  for (int k0 = 0; k0 < K; k0 += BK) {
#pragma unroll
    for (int i = 0; i < AI; ++i) {
      int c = i * 256 + t;
      int ar = c >> 2;
      int ak = (c & 3) * 8;
      int grow = row0 + ar; if (grow > M - 1) grow = M - 1;
      const unsigned short* g = A + (size_t)grow * K + k0 + ak;
      unsigned short* l = Alds + (size_t)(i * 256 + w * 64) * 8;
      async_copy16(g, l);
    }
#pragma unroll
    for (int i = 0; i < BI; ++i) {
      int c = i * 256 + t;
      int br = c >> 2;
      int bk = (c & 3) * 8;
      const unsigned short* g = BT + (size_t)(col0 + br) * K + k0 + bk;
      unsigned short* l = Blds + (size_t)(i * 256 + w * 64) * 8;
      async_copy16(g, l);
    }
    __syncthreads();
    short8 a[4], b[NACC];
#pragma unroll
    for (int m = 0; m < 4; ++m)
      a[m] = *(const short8*)&Alds[(wr + m * 16 + lrow) * BK + lk];
#pragma unroll
    for (int n = 0; n < NACC; ++n)
      b[n] = *(const short8*)&Blds[(wc + n * 16 + lrow) * BK + lk];
#pragma unroll
    for (int m = 0; m < 4; ++m)
#pragma unroll
      for (int n = 0; n < NACC; ++n)
        acc[m][n] = __builtin_amdgcn_mfma_f32_16x16x32_bf16(a[m], b[n], acc[m][n], 0, 0, 0);
    __syncthreads();
  }
#pragma unroll
  for (int m = 0; m < 4; ++m) {
#pragma unroll
    for (int j = 0; j < 4; ++j) {
      int r = row0 + wr + m * 16 + (lane >> 4) * 4 + j;
      if (r < M) {
#pragma unroll
        for (int n = 0; n < NACC; ++n)
          Cb[(size_t)r * Nn + col0 + wc + n * 16 + lrow] = f2bf(acc[m][n][j]);
      }
    }
  }
}

// ---------------- attention logits (bf16 features) ----------------

__global__ void attn1_kernel(const unsigned short* __restrict__ h1b,
                             const float* __restrict__ a_src, const float* __restrict__ a_dst,
                             float* __restrict__ als, float* __restrict__ ald, int n) {
  int w = threadIdx.x >> 6;
  int node = blockIdx.x * 4 + w;
  if (node >= n) return;
  int lane = threadIdx.x & 63;
  uint2 d = *(const uint2*)&h1b[(size_t)node * HC1 + lane * 4];
  float f0 = bflo(d.x), f1 = bfhi(d.x), f2 = bflo(d.y), f3 = bfhi(d.y);
  float4 as_ = ((const float4*)a_src)[lane];
  float4 ad_ = ((const float4*)a_dst)[lane];
  float ps = f0 * as_.x + f1 * as_.y + f2 * as_.z + f3 * as_.w;
  float pd = f0 * ad_.x + f1 * ad_.y + f2 * ad_.z + f3 * ad_.w;
#pragma unroll
  for (int s = 1; s < 16; s <<= 1) {
    ps += __shfl_xor(ps, s);
    pd += __shfl_xor(pd, s);
  }
  if ((lane & 15) == 0) {
    als[node * HEADS + (lane >> 4)] = ps;
    ald[node * HEADS + (lane >> 4)] = pd;
  }
}

__global__ void attn2_kernel(const unsigned short* __restrict__ h2b,
                             const float* __restrict__ a_src, const float* __restrict__ a_dst,
                             float* __restrict__ als, float* __restrict__ ald, int n) {
  int w = threadIdx.x >> 6;
  int node = blockIdx.x * 4 + w;
  if (node >= n) return;
  int lane = threadIdx.x & 63;
  float v = __uint_as_float(((unsigned int)h2b[(size_t)node * NCLS + lane]) << 16);
  float ps = wave_sum(v * a_src[lane]);
  float pd = wave_sum(v * a_dst[lane]);
  if (lane == 0) { als[node] = ps; ald[node] = pd; }
}

// ---------------- aggregation ----------------
// One wave per node; chunk weights staged in per-wave LDS; gathers batched
// (group-of-8) for memory-level parallelism. No segment max (exact: exp/sum).

__global__ void agg1_kernel(const unsigned short* __restrict__ h1b,
                            const float4* __restrict__ als1, const float4* __restrict__ ald1,
                            const int* __restrict__ rowoff, const int* __restrict__ esrc,
                            const float* __restrict__ b1, unsigned short* __restrict__ hact,
                            int n) {
  __shared__ float wlds[4][256];
  __shared__ int   slds[4][64];
  int w = threadIdx.x >> 6;
  int node = blockIdx.x * 4 + w;
  if (node >= n) return;
  int lane = threadIdx.x & 63;
  int beg = rowoff[node], end = rowoff[node + 1];
  float4 aldn = ald1[node];
  int hsel = lane >> 4;
  float4 acc = {0.f, 0.f, 0.f, 0.f};
  float4 dl  = {0.f, 0.f, 0.f, 0.f};
  for (int base = beg; base < end; base += 64) {
    int cnt = min(64, end - base);
    int e = base + lane;
    if (e < end) {
      int s = esrc[e];
      float4 av = als1[s];
      float v, w0, w1, w2, w3;
      v = av.x + aldn.x; v = fmaxf(v, NEG_SLOPE * v); w0 = __expf(v);
      v = av.y + aldn.y; v = fmaxf(v, NEG_SLOPE * v); w1 = __expf(v);
      v = av.z + aldn.z; v = fmaxf(v, NEG_SLOPE * v); w2 = __expf(v);
      v = av.w + aldn.w; v = fmaxf(v, NEG_SLOPE * v); w3 = __expf(v);
      dl.x += w0; dl.y += w1; dl.z += w2; dl.w += w3;
      slds[w][lane] = s;
      float4 wv = {w0, w1, w2, w3};
      *(float4*)&wlds[w][lane * 4] = wv;
    }
    for (int j0 = 0; j0 < cnt; j0 += 8) {
      int g = cnt - j0;
      uint2 d[8]; float wj[8];
#pragma unroll
      for (int jj = 0; jj < 8; ++jj) {
        if (jj < g) {
          int ss = slds[w][j0 + jj];                       // uniform-addr broadcast
          wj[jj] = wlds[w][(j0 + jj) * 4 + hsel];
          d[jj] = *(const uint2*)&h1b[(size_t)ss * HC1 + lane * 4];
        }
      }
#pragma unroll
      for (int jj = 0; jj < 8; ++jj) {
        if (jj < g) {
          acc.x += wj[jj] * bflo(d[jj].x);
          acc.y += wj[jj] * bfhi(d[jj].x);
          acc.z += wj[jj] * bflo(d[jj].y);
          acc.w += wj[jj] * bfhi(d[jj].y);
        }
      }
    }
  }
  float d0 = wave_sum(dl.x), d1 = wave_sum(dl.y);
  float d2 = wave_sum(dl.z), d3 = wave_sum(dl.w);
  float den = hsel < 2 ? (hsel == 0 ? d0 : d1) : (hsel == 2 ? d2 : d3);
  float rden = 1.f / (den + EPS_DENOM);
  float4 bv = ((const float4*)b1)[lane];
  float o0 = acc.x * rden + bv.x;
  float o1 = acc.y * rden + bv.y;
  float o2 = acc.z * rden + bv.z;
  float o3 = acc.w * rden + bv.w;
  o0 = o0 > 0.f ? o0 : __expf(o0) - 1.f;   // ELU
  o1 = o1 > 0.f ? o1 : __expf(o1) - 1.f;
  o2 = o2 > 0.f ? o2 : __expf(o2) - 1.f;
  o3 = o3 > 0.f ? o3 : __expf(o3) - 1.f;
  ushort4 ov = {f2bf(o0), f2bf(o1), f2bf(o2), f2bf(o3)};
  *(ushort4*)&hact[(size_t)node * HC1 + lane * 4] = ov;
}

// agg2: 16-lane groups each handle a different edge (4 edges x 2-unroll = 8 in flight).
__global__ void agg2_kernel(const unsigned short* __restrict__ h2b,
                            const float* __restrict__ als2, const float* __restrict__ ald2,
                            const int* __restrict__ rowoff, const int* __restrict__ esrc,
                            const float* __restrict__ b2, float* __restrict__ out, int n) {
  __shared__ float wlds[4][64];
  __shared__ int   slds[4][64];
  int w = threadIdx.x >> 6;
  int node = blockIdx.x * 4 + w;
  if (node >= n) return;
  int lane = threadIdx.x & 63;
  int g16 = lane >> 4, c = lane & 15;
  int beg = rowoff[node], end = rowoff[node + 1];
  float aldn = ald2[node];
  float4 acc = {0.f, 0.f, 0.f, 0.f};
  float dl = 0.f;
  for (int base = beg; base < end; base += 64) {
    int cnt = min(64, end - base);
    int e = base + lane;
    if (e < end) {
      int s = esrc[e];
      float v = als2[s] + aldn;
      v = fmaxf(v, NEG_SLOPE * v);
      float wl = __expf(v);
      dl += wl;
      slds[w][lane] = s;
      wlds[w][lane] = wl;
    }
    for (int j0 = 0; j0 < cnt; j0 += 8) {
      int i0 = j0 + g16, i1 = j0 + 4 + g16;
      bool v0 = i0 < cnt, v1 = i1 < cnt;
      int ss0 = slds[w][v0 ? i0 : 0];
      int ss1 = slds[w][v1 ? i1 : 0];
      float w0 = wlds[w][v0 ? i0 : 0];
      float w1 = wlds[w][v1 ? i1 : 0];
      if (v0) {
        uint2 dd = *(const uint2*)&h2b[(size_t)ss0 * NCLS + c * 4];
        acc.x += w0 * bflo(dd.x); acc.y += w0 * bfhi(dd.x);
        acc.z += w0 * bflo(dd.y); acc.w += w0 * bfhi(dd.y);
      }
      if (v1) {
        uint2 dd = *(const uint2*)&h2b[(size_t)ss1 * NCLS + c * 4];
        acc.x += w1 * bflo(dd.x); acc.y += w1 * bfhi(dd.x);
        acc.z += w1 * bflo(dd.y); acc.w += w1 * bfhi(dd.y);
      }
    }
  }
  // sum partials across the 4 edge-groups (lanes c, c+16, c+32, c+48)
#pragma unroll
  for (int s = 16; s < 64; s <<= 1) {
    acc.x += __shfl_xor(acc.x, s);
    acc.y += __shfl_xor(acc.y, s);
    acc.z += __shfl_xor(acc.z, s);
    acc.w += __shfl_xor(acc.w, s);
  }
  float den = wave_sum(dl);
  float rden = 1.f / (den + EPS_DENOM);
  float4 bv = *(const float4*)&b2[c * 4];
  float o0 = acc.x * rden + bv.x;
  float o1 = acc.y * rden + bv.y;
  float o2 = acc.z * rden + bv.z;
  float o3 = acc.w * rden + bv.w;
  // log_softmax over 64 classes: reduce within 16-lane group (4 ch per lane)
  float mx = fmaxf(fmaxf(o0, o1), fmaxf(o2, o3));
#pragma unroll
  for (int s = 1; s < 16; s <<= 1) mx = fmaxf(mx, __shfl_xor(mx, s));
  float sm = __expf(o0 - mx) + __expf(o1 - mx) + __expf(o2 - mx) + __expf(o3 - mx);
#pragma unroll
  for (int s = 1; s < 16; s <<= 1) sm += __shfl_xor(sm, s);
  float ls = mx + __logf(sm);
  if (g16 == 0) {
    float4 ov = {o0 - ls, o1 - ls, o2 - ls, o3 - ls};
    *(float4*)&out[(size_t)node * NCLS + c * 4] = ov;
  }
}

// ---------------- launch ----------------

extern "C" void kernel_launch(void* const* d_in, const int* in_sizes, int n_in,
                              void* d_out, int out_size, void* d_ws, size_t ws_size,
                              hipStream_t stream) {
  const float* x      = (const float*)d_in[0];
  const int*   eidx   = (const int*)d_in[1];
  const float* W1     = (const float*)d_in[2];
  const float* a_src1 = (const float*)d_in[3];
  const float* a_dst1 = (const float*)d_in[4];
  const float* b1     = (const float*)d_in[5];
  const float* W2     = (const float*)d_in[6];
  const float* a_src2 = (const float*)d_in[7];
  const float* a_dst2 = (const float*)d_in[8];
  const float* b2     = (const float*)d_in[9];
  float* out = (float*)d_out;

  const int Nn = in_sizes[0] / F_IN;   // 50000
  const int E  = in_sizes[1] / 2;      // 800000
  const int* esrc_in = eidx;
  const int* edst_in = eidx + E;

  char* ws = (char*)d_ws;
  size_t off = 0;
  auto alloc = [&](size_t bytes) -> void* {
    void* p = ws + off;
    off += (bytes + 255) & ~(size_t)255;
    return p;
  };
  unsigned short* h1b    = (unsigned short*)alloc((size_t)Nn * HC1 * sizeof(short));
  unsigned short* hact   = (unsigned short*)alloc((size_t)Nn * HC1 * sizeof(short));
  unsigned short* h2b    = (unsigned short*)alloc((size_t)Nn * NCLS * sizeof(short));
  unsigned short* W1T    = (unsigned short*)alloc((size_t)F_IN * HC1 * sizeof(short));
  unsigned short* W2T    = (unsigned short*)alloc((size_t)HC1 * NCLS * sizeof(short));
  float*          als1   = (float*)alloc((size_t)Nn * HEADS * sizeof(float));
  float*          ald1   = (float*)alloc((size_t)Nn * HEADS * sizeof(float));
  float*          als2   = (float*)alloc((size_t)Nn * sizeof(float));
  float*          ald2   = (float*)alloc((size_t)Nn * sizeof(float));
  int*            cnt    = (int*)alloc((size_t)Nn * sizeof(int));
  int*            rowoff = (int*)alloc((size_t)(Nn + 1) * sizeof(int));
  int*            cursor = (int*)alloc((size_t)Nn * sizeof(int));
  int*            bsum   = (int*)alloc(256 * sizeof(int));
  int*            esrc   = (int*)alloc((size_t)(E + Nn) * sizeof(int));

  const int nscan = (Nn + 1023) / 1024;

  // weight casts (small)
  castT_kernel<<<(F_IN * HC1 + 255) / 256, 256, 0, stream>>>(W1, W1T, F_IN, HC1);
  castT_kernel<<<(HC1 * NCLS + 255) / 256, 256, 0, stream>>>(W2, W2T, HC1, NCLS);

  // CSR build (by destination), reused by both layers
  hipMemsetAsync(cnt, 0, (size_t)Nn * sizeof(int), stream);
  hist_kernel<<<(E + 255) / 256, 256, 0, stream>>>(edst_in, E, cnt);
  scan_blocks_kernel<<<nscan, 1024, 0, stream>>>(cnt, Nn, rowoff, cursor, bsum);
  scan_partials_kernel<<<1, 64, 0, stream>>>(bsum, nscan);
  scan_add_kernel<<<nscan, 1024, 0, stream>>>(Nn, rowoff, cursor, bsum);
  scatter_kernel<<<(E + Nn + 255) / 256, 256, 0, stream>>>(esrc_in, edst_in, E, Nn, cursor, esrc);

  // layer 1: h1 = x @ W1 (fused fp32->bf16 staging)
  {
    dim3 g(HC1 / 128, (Nn + 127) / 128);
    gemm1_fused_kernel<<<g, 256, 0, stream>>>(x, W1T, h1b, Nn);
  }
  {
    int blocks = (Nn + 3) / 4;
    attn1_kernel<<<blocks, 256, 0, stream>>>(h1b, a_src1, a_dst1, als1, ald1, Nn);
    agg1_kernel<<<blocks, 256, 0, stream>>>(h1b, (const float4*)als1, (const float4*)ald1,
                                            rowoff, esrc, b1, hact, Nn);
  }

  // layer 2
  {
    dim3 g(NCLS / 64, (Nn + 127) / 128);
    mfma_gemm_kernel<64><<<g, 256, 0, stream>>>(hact, W2T, h2b, Nn, NCLS, HC1);
  }
  {
    int blocks = (Nn + 3) / 4;
    attn2_kernel<<<blocks, 256, 0, stream>>>(h2b, a_src2, a_dst2, als2, ald2, Nn);
    agg2_kernel<<<blocks, 256, 0, stream>>>(h2b, als2, ald2, rowoff, esrc, b2, out, Nn);
  }
}

// Round 5
// 279.484 us; speedup vs baseline: 4.2152x; 1.0239x over previous
//
#include <hip/hip_runtime.h>
#include <math.h>

#define F_IN 512
#define HC1 256   // HEADS*HID
#define HEADS 4
#define HID 64
#define NCLS 64
#define NEG_SLOPE 0.2f
#define EPS_DENOM 1e-16f

using short8 = __attribute__((ext_vector_type(8))) short;
using f32x4  = __attribute__((ext_vector_type(4))) float;

__device__ inline float wave_sum(float v) {
#pragma unroll
  for (int s = 32; s > 0; s >>= 1) v += __shfl_xor(v, s);
  return v;
}

__device__ inline unsigned short f2bf(float f) {
  unsigned int u = __float_as_uint(f);
  u = (u + 0x7FFF + ((u >> 16) & 1)) >> 16;   // RNE
  return (unsigned short)u;
}
__device__ inline float bflo(unsigned int u) { return __uint_as_float(u << 16); }
__device__ inline float bfhi(unsigned int u) { return __uint_as_float(u & 0xFFFF0000u); }

__device__ inline unsigned int cvtpk_bf16(float lo, float hi) {
  unsigned int r;
  asm("v_cvt_pk_bf16_f32 %0, %1, %2" : "=v"(r) : "v"(lo), "v"(hi));
  return r;
}

__device__ inline void async_copy16(const void* g, void* l) {
  __builtin_amdgcn_global_load_lds((const __attribute__((address_space(1))) void*)g,
                                   (__attribute__((address_space(3))) void*)l, 16, 0, 0);
}

// ---------------- weight transpose-cast (small) ----------------
__global__ void castT_kernel(const float* __restrict__ W, unsigned short* __restrict__ WT,
                             int K, int Nn) {
  int id = blockIdx.x * blockDim.x + threadIdx.x;
  if (id >= K * Nn) return;
  int n = id / K, k = id % K;
  WT[id] = f2bf(W[(size_t)k * Nn + n]);
}

// ---------------- CSR build ----------------

__global__ void hist_kernel(const int* __restrict__ dst, int E, int* __restrict__ cnt) {
  int i = blockIdx.x * blockDim.x + threadIdx.x;
  int stride = gridDim.x * blockDim.x;
  for (int e = i; e < E; e += stride) atomicAdd(&cnt[dst[e]], 1);
}

__global__ void scan_blocks_kernel(const int* __restrict__ cnt, int n,
                                   int* __restrict__ rowoff, int* __restrict__ cursor,
                                   int* __restrict__ bsum) {
  __shared__ int wpart[16];
  int b = blockIdx.x, tid = threadIdx.x;
  int i = b * 1024 + tid;
  int lane = tid & 63, wid = tid >> 6;
  int v = (i < n) ? (cnt[i] + 1) : 0;   // +1 = self loop
  int x = v;
#pragma unroll
  for (int s = 1; s < 64; s <<= 1) {
    int t = __shfl_up(x, s);
    if (lane >= s) x += t;
  }
  if (lane == 63) wpart[wid] = x;
  __syncthreads();
  if (wid == 0) {
    int p = (lane < 16) ? wpart[lane] : 0;
#pragma unroll
    for (int s = 1; s < 16; s <<= 1) {
      int t = __shfl_up(p, s);
      if (lane >= s) p += t;
    }
    if (lane < 16) wpart[lane] = p;
  }
  __syncthreads();
  int incl = x + (wid ? wpart[wid - 1] : 0);
  if (i < n) { rowoff[i + 1] = incl; cursor[i] = incl - v; }
  if (tid == 1023) bsum[b] = incl;
  if (b == 0 && tid == 0) rowoff[0] = 0;
}

__global__ void scan_partials_kernel(int* __restrict__ bsum, int nb) {
  int lane = threadIdx.x;
  int v = (lane < nb) ? bsum[lane] : 0;
  int x = v;
#pragma unroll
  for (int s = 1; s < 64; s <<= 1) {
    int t = __shfl_up(x, s);
    if (lane >= s) x += t;
  }
  if (lane < nb) bsum[lane] = x - v;   // exclusive
}

__global__ void scan_add_kernel(int n, int* __restrict__ rowoff, int* __restrict__ cursor,
                                const int* __restrict__ bsum) {
  int i = blockIdx.x * 1024 + threadIdx.x;
  int off = bsum[blockIdx.x];
  if (i < n) { rowoff[i + 1] += off; cursor[i] += off; }
}

__global__ void scatter_kernel(const int* __restrict__ src, const int* __restrict__ dst,
                               int E, int n, int* __restrict__ cursor, int* __restrict__ esrc) {
  int i = blockIdx.x * blockDim.x + threadIdx.x;
  int stride = gridDim.x * blockDim.x;
  for (int e = i; e < E + n; e += stride) {
    int s, d;
    if (e < E) { s = src[e]; d = dst[e]; } else { s = e - E; d = s; }
    int pos = atomicAdd(&cursor[d], 1);
    esrc[pos] = s;
  }
}

// ---------------- GEMM1: fused fp32->bf16 A-staging, bf16 MFMA ----------------

__global__ __launch_bounds__(256)
void gemm1_fused_kernel(const float* __restrict__ A, const unsigned short* __restrict__ BT,
                        unsigned short* __restrict__ Cb, int M) {
  constexpr int BM = 128, BN = 128, BK = 32, K = F_IN, Nn = HC1;
  __shared__ unsigned short Alds[BM * BK];
  __shared__ unsigned short Blds[BN * BK];
  const int t = threadIdx.x;
  const int lane = t & 63;
  const int w = t >> 6;
  const int wr = (w >> 1) * 64;
  const int wc = (w & 1) * 64;
  const int row0 = blockIdx.y * BM;
  const int col0 = blockIdx.x * BN;
  const int lrow = lane & 15;
  const int lk = (lane >> 4) * 8;

  f32x4 acc[4][4] = {};
  const int ar = t >> 1;
  const int kh = (t & 1) * 16;
  int grow = row0 + ar; if (grow > M - 1) grow = M - 1;
  const float* arow = A + (size_t)grow * K + kh;

  for (int k0 = 0; k0 < K; k0 += BK) {
#pragma unroll
    for (int i = 0; i < 2; ++i) {
      int c = i * 256 + t;
      int br = c >> 2;
      int bk = (c & 3) * 8;
      const unsigned short* g = BT + (size_t)(col0 + br) * K + k0 + bk;
      unsigned short* l = Blds + (size_t)(i * 256 + w * 64) * 8;
      async_copy16(g, l);
    }
    const float4* gp = (const float4*)(arow + k0);
    float4 f0 = gp[0], f1 = gp[1], f2 = gp[2], f3 = gp[3];
    uint4 u0, u1;
    u0.x = cvtpk_bf16(f0.x, f0.y); u0.y = cvtpk_bf16(f0.z, f0.w);
    u0.z = cvtpk_bf16(f1.x, f1.y); u0.w = cvtpk_bf16(f1.z, f1.w);
    u1.x = cvtpk_bf16(f2.x, f2.y); u1.y = cvtpk_bf16(f2.z, f2.w);
    u1.z = cvtpk_bf16(f3.x, f3.y); u1.w = cvtpk_bf16(f3.z, f3.w);
    uint4* dstp = (uint4*)&Alds[ar * BK + kh];
    dstp[0] = u0; dstp[1] = u1;
    __syncthreads();
    short8 a[4], b[4];
#pragma unroll
    for (int m = 0; m < 4; ++m)
      a[m] = *(const short8*)&Alds[(wr + m * 16 + lrow) * BK + lk];
#pragma unroll
    for (int n = 0; n < 4; ++n)
      b[n] = *(const short8*)&Blds[(wc + n * 16 + lrow) * BK + lk];
#pragma unroll
    for (int m = 0; m < 4; ++m)
#pragma unroll
      for (int n = 0; n < 4; ++n)
        acc[m][n] = __builtin_amdgcn_mfma_f32_16x16x32_bf16(a[m], b[n], acc[m][n], 0, 0, 0);
    __syncthreads();
  }
#pragma unroll
  for (int m = 0; m < 4; ++m) {
#pragma unroll
    for (int j = 0; j < 4; ++j) {
      int r = row0 + wr + m * 16 + (lane >> 4) * 4 + j;
      if (r < M) {
#pragma unroll
        for (int n = 0; n < 4; ++n)
          Cb[(size_t)r * Nn + col0 + wc + n * 16 + lrow] = f2bf(acc[m][n][j]);
      }
    }
  }
}

// ---------------- GEMM2: bf16 A (m97-structure) ----------------

template <int BN>
__global__ __launch_bounds__(256)
void mfma_gemm_kernel(const unsigned short* __restrict__ A,
                      const unsigned short* __restrict__ BT,
                      unsigned short* __restrict__ Cb, int M, int Nn, int K) {
  constexpr int BM = 128, BK = 32;
  constexpr int NACC = BN / 32;
  __shared__ unsigned short Alds[BM * BK];
  __shared__ unsigned short Blds[BN * BK];
  const int t = threadIdx.x;
  const int lane = t & 63;
  const int w = t >> 6;
  const int wr = (w >> 1) * 64;
  const int wc = (w & 1) * (BN / 2);
  const int row0 = blockIdx.y * BM;
  const int col0 = blockIdx.x * BN;
  const int lrow = lane & 15;
  const int lk = (lane >> 4) * 8;

  f32x4 acc[4][NACC] = {};
  constexpr int AI = (BM * BK) / (256 * 8);
  constexpr int BI = (BN * BK) / (256 * 8);

  for (int k0 = 0; k0 < K; k0 += BK) {
#pragma unroll
    for (int i = 0; i < AI; ++i) {
      int c = i * 256 + t;
      int ar = c >> 2;
      int ak = (c & 3) * 8;
      int grow = row0 + ar; if (grow > M - 1) grow = M - 1;
      const unsigned short* g = A + (size_t)grow * K + k0 + ak;
      unsigned short* l = Alds + (size_t)(i * 256 + w * 64) * 8;
      async_copy16(g, l);
    }
#pragma unroll
    for (int i = 0; i < BI; ++i) {
      int c = i * 256 + t;
      int br = c >> 2;
      int bk = (c & 3) * 8;
      const unsigned short* g = BT + (size_t)(col0 + br) * K + k0 + bk;
      unsigned short* l = Blds + (size_t)(i * 256 + w * 64) * 8;
      async_copy16(g, l);
    }
    __syncthreads();
    short8 a[4], b[NACC];
#pragma unroll
    for (int m = 0; m < 4; ++m)
      a[m] = *(const short8*)&Alds[(wr + m * 16 + lrow) * BK + lk];
#pragma unroll
    for (int n = 0; n < NACC; ++n)
      b[n] = *(const short8*)&Blds[(wc + n * 16 + lrow) * BK + lk];
#pragma unroll
    for (int m = 0; m < 4; ++m)
#pragma unroll
      for (int n = 0; n < NACC; ++n)
        acc[m][n] = __builtin_amdgcn_mfma_f32_16x16x32_bf16(a[m], b[n], acc[m][n], 0, 0, 0);
    __syncthreads();
  }
#pragma unroll
  for (int m = 0; m < 4; ++m) {
#pragma unroll
    for (int j = 0; j < 4; ++j) {
      int r = row0 + wr + m * 16 + (lane >> 4) * 4 + j;
      if (r < M) {
#pragma unroll
        for (int n = 0; n < NACC; ++n)
          Cb[(size_t)r * Nn + col0 + wc + n * 16 + lrow] = f2bf(acc[m][n][j]);
      }
    }
  }
}

// ---------------- attention logits ----------------

__global__ void attn1_kernel(const unsigned short* __restrict__ h1b,
                             const float* __restrict__ a_src, const float* __restrict__ a_dst,
                             float* __restrict__ als, float* __restrict__ ald, int n) {
  int w = threadIdx.x >> 6;
  int node = blockIdx.x * 4 + w;
  if (node >= n) return;
  int lane = threadIdx.x & 63;
  uint2 d = *(const uint2*)&h1b[(size_t)node * HC1 + lane * 4];
  float f0 = bflo(d.x), f1 = bfhi(d.x), f2 = bflo(d.y), f3 = bfhi(d.y);
  float4 as_ = ((const float4*)a_src)[lane];
  float4 ad_ = ((const float4*)a_dst)[lane];
  float ps = f0 * as_.x + f1 * as_.y + f2 * as_.z + f3 * as_.w;
  float pd = f0 * ad_.x + f1 * ad_.y + f2 * ad_.z + f3 * ad_.w;
#pragma unroll
  for (int s = 1; s < 16; s <<= 1) {
    ps += __shfl_xor(ps, s);
    pd += __shfl_xor(pd, s);
  }
  if ((lane & 15) == 0) {
    als[node * HEADS + (lane >> 4)] = ps;
    ald[node * HEADS + (lane >> 4)] = pd;
  }
}

__global__ void attn2_kernel(const unsigned short* __restrict__ h2b,
                             const float* __restrict__ a_src, const float* __restrict__ a_dst,
                             float* __restrict__ als, float* __restrict__ ald, int n) {
  int w = threadIdx.x >> 6;
  int node = blockIdx.x * 4 + w;
  if (node >= n) return;
  int lane = threadIdx.x & 63;
  float v = __uint_as_float(((unsigned int)h2b[(size_t)node * NCLS + lane]) << 16);
  float ps = wave_sum(v * a_src[lane]);
  float pd = wave_sum(v * a_dst[lane]);
  if (lane == 0) { als[node] = ps; ald[node] = pd; }
}

// ---------------- aggregation ----------------
// agg1: one wave per node. One gather instruction covers TWO edges:
// lanes 0-31 = edge j, lanes 32-63 = edge j+1, 16B/lane (8 channels).
// Batches of 4 instructions (8 edges), ping-ponged (8 instrs = 8KB in flight).

__global__ void agg1_kernel(const unsigned short* __restrict__ h1b,
                            const float4* __restrict__ als1, const float4* __restrict__ ald1,
                            const int* __restrict__ rowoff, const int* __restrict__ esrc,
                            const float* __restrict__ b1, unsigned short* __restrict__ hact,
                            int n) {
  __shared__ float wlds[4][256];
  __shared__ int   slds[4][64];
  int w = threadIdx.x >> 6;
  int node = blockIdx.x * 4 + w;
  if (node >= n) return;
  int lane = threadIdx.x & 63;
  int hi = lane >> 5;        // which of the 2 edges in an instruction
  int cl = lane & 31;        // channel-lane: channels cl*8 .. cl*8+7
  int head = cl >> 3;
  int beg = rowoff[node], end = rowoff[node + 1];
  float4 aldn = ald1[node];
  f32x4 accA = {0.f, 0.f, 0.f, 0.f};   // channels cl*8+0..3
  f32x4 accB = {0.f, 0.f, 0.f, 0.f};   // channels cl*8+4..7
  float dl0 = 0.f, dl1 = 0.f, dl2 = 0.f, dl3 = 0.f;

  for (int base = beg; base < end; base += 64) {
    int cnt = min(64, end - base);
    if (lane < cnt) {
      int s = esrc[base + lane];
      float4 av = als1[s];
      float v, w0, w1, w2, w3;
      v = av.x + aldn.x; v = fmaxf(v, NEG_SLOPE * v); w0 = __expf(v);
      v = av.y + aldn.y; v = fmaxf(v, NEG_SLOPE * v); w1 = __expf(v);
      v = av.z + aldn.z; v = fmaxf(v, NEG_SLOPE * v); w2 = __expf(v);
      v = av.w + aldn.w; v = fmaxf(v, NEG_SLOPE * v); w3 = __expf(v);
      dl0 += w0; dl1 += w1; dl2 += w2; dl3 += w3;
      slds[w][lane] = s;
      float4 wv = {w0, w1, w2, w3};
      *(float4*)&wlds[w][lane * 4] = wv;
    }

    uint4 dA[4], dB[4];
    float wA[4], wB[4];
    auto ISSUE = [&](int j0, uint4* d, float* wj) {
#pragma unroll
      for (int ii = 0; ii < 4; ++ii) {
        int e = j0 + 2 * ii + hi;
        bool val = e < cnt;
        int se = val ? e : 0;
        int ss = slds[w][se];
        wj[ii] = val ? wlds[w][se * 4 + head] : 0.f;
        d[ii] = *(const uint4*)&h1b[(size_t)ss * HC1 + cl * 8];
      }
    };
    auto CONSUME = [&](const uint4* d, const float* wj) {
#pragma unroll
      for (int ii = 0; ii < 4; ++ii) {
        float q = wj[ii];
        accA[0] += q * bflo(d[ii].x); accA[1] += q * bfhi(d[ii].x);
        accA[2] += q * bflo(d[ii].y); accA[3] += q * bfhi(d[ii].y);
        accB[0] += q * bflo(d[ii].z); accB[1] += q * bfhi(d[ii].z);
        accB[2] += q * bflo(d[ii].w); accB[3] += q * bfhi(d[ii].w);
      }
    };

    ISSUE(0, dA, wA);
    for (int j0 = 8;; j0 += 16) {
      bool hasB = j0 < cnt;
      if (hasB) ISSUE(j0, dB, wB);
      CONSUME(dA, wA);
      if (!hasB) break;
      bool hasA = (j0 + 8) < cnt;
      if (hasA) ISSUE(j0 + 8, dA, wA);
      CONSUME(dB, wB);
      if (!hasA) break;
    }
  }

  // combine the two edge-halves (lanes l and l^32 hold same channels)
#pragma unroll
  for (int k = 0; k < 4; ++k) {
    accA[k] += __shfl_xor(accA[k], 32);
    accB[k] += __shfl_xor(accB[k], 32);
  }
  float d0 = wave_sum(dl0), d1 = wave_sum(dl1);
  float d2 = wave_sum(dl2), d3 = wave_sum(dl3);
  float den = head < 2 ? (head == 0 ? d0 : d1) : (head == 2 ? d2 : d3);
  float rden = 1.f / (den + EPS_DENOM);
  if (hi == 0) {
    float4 bv0 = *(const float4*)&b1[cl * 8];
    float4 bv1 = *(const float4*)&b1[cl * 8 + 4];
    float o[8];
    o[0] = accA[0] * rden + bv0.x; o[1] = accA[1] * rden + bv0.y;
    o[2] = accA[2] * rden + bv0.z; o[3] = accA[3] * rden + bv0.w;
    o[4] = accB[0] * rden + bv1.x; o[5] = accB[1] * rden + bv1.y;
    o[6] = accB[2] * rden + bv1.z; o[7] = accB[3] * rden + bv1.w;
    ushort4 ov0, ov1;
#pragma unroll
    for (int k = 0; k < 8; ++k) o[k] = o[k] > 0.f ? o[k] : __expf(o[k]) - 1.f;  // ELU
    ov0.x = f2bf(o[0]); ov0.y = f2bf(o[1]); ov0.z = f2bf(o[2]); ov0.w = f2bf(o[3]);
    ov1.x = f2bf(o[4]); ov1.y = f2bf(o[5]); ov1.z = f2bf(o[6]); ov1.w = f2bf(o[7]);
    *(ushort4*)&hact[(size_t)node * HC1 + cl * 8] = ov0;
    *(ushort4*)&hact[(size_t)node * HC1 + cl * 8 + 4] = ov1;
  }
}

// agg2: one instruction covers 8 edges (8-lane groups, 16B/lane over the 128B row).
__global__ void agg2_kernel(const unsigned short* __restrict__ h2b,
                            const float* __restrict__ als2, const float* __restrict__ ald2,
                            const int* __restrict__ rowoff, const int* __restrict__ esrc,
                            const float* __restrict__ b2, float* __restrict__ out, int n) {
  __shared__ float wlds[4][64];
  __shared__ int   slds[4][64];
  int w = threadIdx.x >> 6;
  int node = blockIdx.x * 4 + w;
  if (node >= n) return;
  int lane = threadIdx.x & 63;
  int eg = lane >> 3;      // edge-group 0..7
  int cl = lane & 7;       // channels cl*8 .. cl*8+7
  int beg = rowoff[node], end = rowoff[node + 1];
  float aldn = ald2[node];
  f32x4 accA = {0.f, 0.f, 0.f, 0.f};
  f32x4 accB = {0.f, 0.f, 0.f, 0.f};
  float dl = 0.f;
  for (int base = beg; base < end; base += 64) {
    int cnt = min(64, end - base);
    if (lane < cnt) {
      int s = esrc[base + lane];
      float v = als2[s] + aldn;
      v = fmaxf(v, NEG_SLOPE * v);
      float wl = __expf(v);
      dl += wl;
      slds[w][lane] = s;
      wlds[w][lane] = wl;
    }
    for (int j0 = 0; j0 < cnt; j0 += 32) {
      uint4 d[4]; float wj[4];
#pragma unroll
      for (int ii = 0; ii < 4; ++ii) {
        int e = j0 + ii * 8 + eg;
        bool val = e < cnt;
        int se = val ? e : 0;
        int ss = slds[w][se];
        wj[ii] = val ? wlds[w][se] : 0.f;
        d[ii] = *(const uint4*)&h2b[(size_t)ss * NCLS + cl * 8];
      }
#pragma unroll
      for (int ii = 0; ii < 4; ++ii) {
        float q = wj[ii];
        accA[0] += q * bflo(d[ii].x); accA[1] += q * bfhi(d[ii].x);
        accA[2] += q * bflo(d[ii].y); accA[3] += q * bfhi(d[ii].y);
        accB[0] += q * bflo(d[ii].z); accB[1] += q * bfhi(d[ii].z);
        accB[2] += q * bflo(d[ii].w); accB[3] += q * bfhi(d[ii].w);
      }
    }
  }
  // combine across the 8 edge-groups (lanes sharing cl)
#pragma unroll
  for (int s = 8; s < 64; s <<= 1) {
#pragma unroll
    for (int k = 0; k < 4; ++k) {
      accA[k] += __shfl_xor(accA[k], s);
      accB[k] += __shfl_xor(accB[k], s);
    }
  }
  float den = wave_sum(dl);
  float rden = 1.f / (den + EPS_DENOM);
  float4 bv0 = *(const float4*)&b2[cl * 8];
  float4 bv1 = *(const float4*)&b2[cl * 8 + 4];
  float o[8];
  o[0] = accA[0] * rden + bv0.x; o[1] = accA[1] * rden + bv0.y;
  o[2] = accA[2] * rden + bv0.z; o[3] = accA[3] * rden + bv0.w;
  o[4] = accB[0] * rden + bv1.x; o[5] = accB[1] * rden + bv1.y;
  o[6] = accB[2] * rden + bv1.z; o[7] = accB[3] * rden + bv1.w;
  // log_softmax over 64 classes: in-lane max/sum of 8, then across the 8 cl-groups
  float mx = o[0];
#pragma unroll
  for (int k = 1; k < 8; ++k) mx = fmaxf(mx, o[k]);
#pragma unroll
  for (int s = 1; s < 8; s <<= 1) mx = fmaxf(mx, __shfl_xor(mx, s));
  float sm = 0.f;
#pragma unroll
  for (int k = 0; k < 8; ++k) sm += __expf(o[k] - mx);
#pragma unroll
  for (int s = 1; s < 8; s <<= 1) sm += __shfl_xor(sm, s);
  float ls = mx + __logf(sm);
  if (lane < 8) {
    float4 q0 = {o[0] - ls, o[1] - ls, o[2] - ls, o[3] - ls};
    float4 q1 = {o[4] - ls, o[5] - ls, o[6] - ls, o[7] - ls};
    *(float4*)&out[(size_t)node * NCLS + cl * 8] = q0;
    *(float4*)&out[(size_t)node * NCLS + cl * 8 + 4] = q1;
  }
}

// ---------------- launch ----------------

extern "C" void kernel_launch(void* const* d_in, const int* in_sizes, int n_in,
                              void* d_out, int out_size, void* d_ws, size_t ws_size,
                              hipStream_t stream) {
  const float* x      = (const float*)d_in[0];
  const int*   eidx   = (const int*)d_in[1];
  const float* W1     = (const float*)d_in[2];
  const float* a_src1 = (const float*)d_in[3];
  const float* a_dst1 = (const float*)d_in[4];
  const float* b1     = (const float*)d_in[5];
  const float* W2     = (const float*)d_in[6];
  const float* a_src2 = (const float*)d_in[7];
  const float* a_dst2 = (const float*)d_in[8];
  const float* b2     = (const float*)d_in[9];
  float* out = (float*)d_out;

  const int Nn = in_sizes[0] / F_IN;   // 50000
  const int E  = in_sizes[1] / 2;      // 800000
  const int* esrc_in = eidx;
  const int* edst_in = eidx + E;

  char* ws = (char*)d_ws;
  size_t off = 0;
  auto alloc = [&](size_t bytes) -> void* {
    void* p = ws + off;
    off += (bytes + 255) & ~(size_t)255;
    return p;
  };
  unsigned short* h1b    = (unsigned short*)alloc((size_t)Nn * HC1 * sizeof(short));
  unsigned short* hact   = (unsigned short*)alloc((size_t)Nn * HC1 * sizeof(short));
  unsigned short* h2b    = (unsigned short*)alloc((size_t)Nn * NCLS * sizeof(short));
  unsigned short* W1T    = (unsigned short*)alloc((size_t)F_IN * HC1 * sizeof(short));
  unsigned short* W2T    = (unsigned short*)alloc((size_t)HC1 * NCLS * sizeof(short));
  float*          als1   = (float*)alloc((size_t)Nn * HEADS * sizeof(float));
  float*          ald1   = (float*)alloc((size_t)Nn * HEADS * sizeof(float));
  float*          als2   = (float*)alloc((size_t)Nn * sizeof(float));
  float*          ald2   = (float*)alloc((size_t)Nn * sizeof(float));
  int*            cnt    = (int*)alloc((size_t)Nn * sizeof(int));
  int*            rowoff = (int*)alloc((size_t)(Nn + 1) * sizeof(int));
  int*            cursor = (int*)alloc((size_t)Nn * sizeof(int));
  int*            bsum   = (int*)alloc(256 * sizeof(int));
  int*            esrc   = (int*)alloc((size_t)(E + Nn) * sizeof(int));

  const int nscan = (Nn + 1023) / 1024;

  castT_kernel<<<(F_IN * HC1 + 255) / 256, 256, 0, stream>>>(W1, W1T, F_IN, HC1);
  castT_kernel<<<(HC1 * NCLS + 255) / 256, 256, 0, stream>>>(W2, W2T, HC1, NCLS);

  hipMemsetAsync(cnt, 0, (size_t)Nn * sizeof(int), stream);
  hist_kernel<<<(E + 255) / 256, 256, 0, stream>>>(edst_in, E, cnt);
  scan_blocks_kernel<<<nscan, 1024, 0, stream>>>(cnt, Nn, rowoff, cursor, bsum);
  scan_partials_kernel<<<1, 64, 0, stream>>>(bsum, nscan);
  scan_add_kernel<<<nscan, 1024, 0, stream>>>(Nn, rowoff, cursor, bsum);
  scatter_kernel<<<(E + Nn + 255) / 256, 256, 0, stream>>>(esrc_in, edst_in, E, Nn, cursor, esrc);

  // layer 1
  {
    dim3 g(HC1 / 128, (Nn + 127) / 128);
    gemm1_fused_kernel<<<g, 256, 0, stream>>>(x, W1T, h1b, Nn);
  }
  {
    int blocks = (Nn + 3) / 4;
    attn1_kernel<<<blocks, 256, 0, stream>>>(h1b, a_src1, a_dst1, als1, ald1, Nn);
    agg1_kernel<<<blocks, 256, 0, stream>>>(h1b, (const float4*)als1, (const float4*)ald1,
                                            rowoff, esrc, b1, hact, Nn);
  }

  // layer 2
  {
    dim3 g(NCLS / 64, (Nn + 127) / 128);
    mfma_gemm_kernel<64><<<g, 256, 0, stream>>>(hact, W2T, h2b, Nn, NCLS, HC1);
  }
  {
    int blocks = (Nn + 3) / 4;
    attn2_kernel<<<blocks, 256, 0, stream>>>(h2b, a_src2, a_dst2, als2, ald2, Nn);
    agg2_kernel<<<blocks, 256, 0, stream>>>(h2b, als2, ald2, rowoff, esrc, b2, out, Nn);
  }
}

// Round 6
// 261.368 us; speedup vs baseline: 4.5074x; 1.0693x over previous
//
#include <hip/hip_runtime.h>
#include <math.h>

#define F_IN 512
#define HC1 256   // HEADS*HID
#define HEADS 4
#define HID 64
#define NCLS 64
#define NEG_SLOPE 0.2f
#define EPS_DENOM 1e-16f

using short8 = __attribute__((ext_vector_type(8))) short;
using f32x4  = __attribute__((ext_vector_type(4))) float;

__device__ inline float wave_sum(float v) {
#pragma unroll
  for (int s = 32; s > 0; s >>= 1) v += __shfl_xor(v, s);
  return v;
}

__device__ inline unsigned short f2bf(float f) {
  unsigned int u = __float_as_uint(f);
  u = (u + 0x7FFF + ((u >> 16) & 1)) >> 16;   // RNE
  return (unsigned short)u;
}
__device__ inline float bflo(unsigned int u) { return __uint_as_float(u << 16); }
__device__ inline float bfhi(unsigned int u) { return __uint_as_float(u & 0xFFFF0000u); }

__device__ inline unsigned int cvtpk_bf16(float lo, float hi) {
  unsigned int r;
  asm("v_cvt_pk_bf16_f32 %0, %1, %2" : "=v"(r) : "v"(lo), "v"(hi));
  return r;
}

__device__ inline void async_copy16(const void* g, void* l) {
  __builtin_amdgcn_global_load_lds((const __attribute__((address_space(1))) void*)g,
                                   (__attribute__((address_space(3))) void*)l, 16, 0, 0);
}

// ---------------- weight transpose-cast (small) ----------------
__global__ void castT_kernel(const float* __restrict__ W, unsigned short* __restrict__ WT,
                             int K, int Nn) {
  int id = blockIdx.x * blockDim.x + threadIdx.x;
  if (id >= K * Nn) return;
  int n = id / K, k = id % K;
  WT[id] = f2bf(W[(size_t)k * Nn + n]);
}

// ---------------- CSR build ----------------

__global__ void hist_kernel(const int* __restrict__ dst, int E, int* __restrict__ cnt) {
  int i = blockIdx.x * blockDim.x + threadIdx.x;
  int stride = gridDim.x * blockDim.x;
  for (int e = i; e < E; e += stride) atomicAdd(&cnt[dst[e]], 1);
}

__global__ void scan_blocks_kernel(const int* __restrict__ cnt, int n,
                                   int* __restrict__ rowoff, int* __restrict__ cursor,
                                   int* __restrict__ bsum) {
  __shared__ int wpart[16];
  int b = blockIdx.x, tid = threadIdx.x;
  int i = b * 1024 + tid;
  int lane = tid & 63, wid = tid >> 6;
  int v = (i < n) ? (cnt[i] + 1) : 0;   // +1 = self loop
  int x = v;
#pragma unroll
  for (int s = 1; s < 64; s <<= 1) {
    int t = __shfl_up(x, s);
    if (lane >= s) x += t;
  }
  if (lane == 63) wpart[wid] = x;
  __syncthreads();
  if (wid == 0) {
    int p = (lane < 16) ? wpart[lane] : 0;
#pragma unroll
    for (int s = 1; s < 16; s <<= 1) {
      int t = __shfl_up(p, s);
      if (lane >= s) p += t;
    }
    if (lane < 16) wpart[lane] = p;
  }
  __syncthreads();
  int incl = x + (wid ? wpart[wid - 1] : 0);
  if (i < n) { rowoff[i + 1] = incl; cursor[i] = incl - v; }
  if (tid == 1023) bsum[b] = incl;
  if (b == 0 && tid == 0) rowoff[0] = 0;
}

__global__ void scan_partials_kernel(int* __restrict__ bsum, int nb) {
  int lane = threadIdx.x;
  int v = (lane < nb) ? bsum[lane] : 0;
  int x = v;
#pragma unroll
  for (int s = 1; s < 64; s <<= 1) {
    int t = __shfl_up(x, s);
    if (lane >= s) x += t;
  }
  if (lane < nb) bsum[lane] = x - v;   // exclusive
}

__global__ void scan_add_kernel(int n, int* __restrict__ rowoff, int* __restrict__ cursor,
                                const int* __restrict__ bsum) {
  int i = blockIdx.x * 1024 + threadIdx.x;
  int off = bsum[blockIdx.x];
  if (i < n) { rowoff[i + 1] += off; cursor[i] += off; }
}

__global__ void scatter_kernel(const int* __restrict__ src, const int* __restrict__ dst,
                               int E, int n, int* __restrict__ cursor, int* __restrict__ esrc) {
  int i = blockIdx.x * blockDim.x + threadIdx.x;
  int stride = gridDim.x * blockDim.x;
  for (int e = i; e < E + n; e += stride) {
    int s, d;
    if (e < E) { s = src[e]; d = dst[e]; } else { s = e - E; d = s; }
    int pos = atomicAdd(&cursor[d], 1);
    esrc[pos] = s;
  }
}

// ---------------- GEMM1: x(fp32)@W1 -> h1b(bf16), fused attn1 dots ----------------
// BN=256 = full width: x read once; double-buffered LDS, 1 barrier/iter;
// wave w: rows (w>>2)*64, cols (w&3)*64  ->  head = w&3 owns its full 64-col head.

__global__ __launch_bounds__(512)
void gemm1_fused_kernel(const float* __restrict__ A, const unsigned short* __restrict__ BT,
                        unsigned short* __restrict__ Cb,
                        const float* __restrict__ as1, const float* __restrict__ ad1,
                        float* __restrict__ als, float* __restrict__ ald, int M) {
  constexpr int BM = 128, BN = 256, BK = 32, K = F_IN, Nn = HC1;
  __shared__ unsigned short Alds[2][BM * BK];
  __shared__ unsigned short Blds[2][BN * BK];
  const int t = threadIdx.x;
  const int lane = t & 63;
  const int w = t >> 6;                    // 0..7
  const int wr = (w >> 2) * 64;
  const int wc = (w & 3) * 64;
  const int head = w & 3;
  const int row0 = blockIdx.x * BM;
  const int lrow = lane & 15;
  const int lk = (lane >> 4) * 8;

  f32x4 acc[4][4] = {};

  // A-stage map: row = t>>2, k-quarter = (t&3)*8 (8 floats per thread)
  const int ar = t >> 2, kq = (t & 3) * 8;
  int grow = row0 + ar; if (grow > M - 1) grow = M - 1;
  const float* aptr = A + (size_t)grow * K + kq;

  float4 fa0, fa1;
  // prologue: stage k0=0 into buf 0
  fa0 = *(const float4*)(aptr);
  fa1 = *(const float4*)(aptr + 4);
#pragma unroll
  for (int i = 0; i < 2; ++i) {
    int c = i * 512 + t;
    const unsigned short* g = BT + (size_t)(c >> 2) * K + (c & 3) * 8;
    async_copy16(g, &Blds[0][(size_t)c * 8]);
  }
  {
    uint4 u;
    u.x = cvtpk_bf16(fa0.x, fa0.y); u.y = cvtpk_bf16(fa0.z, fa0.w);
    u.z = cvtpk_bf16(fa1.x, fa1.y); u.w = cvtpk_bf16(fa1.z, fa1.w);
    *(uint4*)&Alds[0][ar * BK + kq] = u;
  }
  int cur = 0;
  for (int k0 = 0; k0 < K; k0 += BK) {
    __syncthreads();                       // buf[cur] staged (vmcnt+lgkm drained)
    const int nxt = cur ^ 1;
    const bool more = (k0 + BK) < K;
    if (more) {
#pragma unroll
      for (int i = 0; i < 2; ++i) {
        int c = i * 512 + t;
        const unsigned short* g = BT + (size_t)(c >> 2) * K + (k0 + BK) + (c & 3) * 8;
        async_copy16(g, &Blds[nxt][(size_t)c * 8]);
      }
      fa0 = *(const float4*)(aptr + k0 + BK);
      fa1 = *(const float4*)(aptr + k0 + BK + 4);
    }
    short8 a[4], b[4];
#pragma unroll
    for (int m = 0; m < 4; ++m)
      a[m] = *(const short8*)&Alds[cur][(wr + m * 16 + lrow) * BK + lk];
#pragma unroll
    for (int n = 0; n < 4; ++n)
      b[n] = *(const short8*)&Blds[cur][(wc + n * 16 + lrow) * BK + lk];
#pragma unroll
    for (int m = 0; m < 4; ++m)
#pragma unroll
      for (int n = 0; n < 4; ++n)
        acc[m][n] = __builtin_amdgcn_mfma_f32_16x16x32_bf16(a[m], b[n], acc[m][n], 0, 0, 0);
    if (more) {
      uint4 u;
      u.x = cvtpk_bf16(fa0.x, fa0.y); u.y = cvtpk_bf16(fa0.z, fa0.w);
      u.z = cvtpk_bf16(fa1.x, fa1.y); u.w = cvtpk_bf16(fa1.z, fa1.w);
      *(uint4*)&Alds[nxt][ar * BK + kq] = u;
    }
    cur = nxt;
  }

  // epilogue: C write + per-head attention dots from f32 accumulators
  float asv[4], adv[4];
#pragma unroll
  for (int n = 0; n < 4; ++n) {
    asv[n] = as1[head * 64 + n * 16 + lrow];
    adv[n] = ad1[head * 64 + n * 16 + lrow];
  }
#pragma unroll
  for (int m = 0; m < 4; ++m) {
#pragma unroll
    for (int j = 0; j < 4; ++j) {
      int r = row0 + wr + m * 16 + (lane >> 4) * 4 + j;
      float ps = 0.f, pd = 0.f;
#pragma unroll
      for (int n = 0; n < 4; ++n) {
        float v = acc[m][n][j];
        ps += v * asv[n];
        pd += v * adv[n];
        if (r < M) Cb[(size_t)r * Nn + wc + n * 16 + lrow] = f2bf(v);
      }
#pragma unroll
      for (int s = 1; s < 16; s <<= 1) {
        ps += __shfl_xor(ps, s);
        pd += __shfl_xor(pd, s);
      }
      if ((lane & 15) == 0 && r < M) {
        als[r * HEADS + head] = ps;
        ald[r * HEADS + head] = pd;
      }
    }
  }
}

// ---------------- GEMM2: hact(bf16)@W2 -> h2b(bf16), fused attn2 dots ----------------

__global__ __launch_bounds__(256)
void gemm2_fused_kernel(const unsigned short* __restrict__ A,
                        const unsigned short* __restrict__ BT,
                        unsigned short* __restrict__ Cb,
                        const float* __restrict__ as2, const float* __restrict__ ad2,
                        float* __restrict__ als, float* __restrict__ ald, int M) {
  constexpr int BM = 128, BN = 64, BK = 32, K = HC1, Nn = NCLS;
  __shared__ unsigned short Alds[BM * BK];
  __shared__ unsigned short Blds[BN * BK];
  __shared__ float sps[BM], spd[BM];
  const int t = threadIdx.x;
  const int lane = t & 63;
  const int w = t >> 6;
  const int wr = (w >> 1) * 64;
  const int wc = (w & 1) * 32;
  const int row0 = blockIdx.x * BM;
  const int lrow = lane & 15;
  const int lk = (lane >> 4) * 8;
  if (t < BM) { sps[t] = 0.f; spd[t] = 0.f; }

  f32x4 acc[4][2] = {};
  for (int k0 = 0; k0 < K; k0 += BK) {
#pragma unroll
    for (int i = 0; i < 2; ++i) {
      int c = i * 256 + t;
      int arr = c >> 2;
      int ak = (c & 3) * 8;
      int grow = row0 + arr; if (grow > M - 1) grow = M - 1;
      const unsigned short* g = A + (size_t)grow * K + k0 + ak;
      unsigned short* l = Alds + (size_t)(i * 256 + w * 64) * 8;
      async_copy16(g, l);
    }
    {
      int c = t;
      int br = c >> 2;
      int bk = (c & 3) * 8;
      const unsigned short* g = BT + (size_t)br * K + k0 + bk;
      unsigned short* l = Blds + (size_t)(w * 64) * 8;
      async_copy16(g, l);
    }
    __syncthreads();
    short8 a[4], b[2];
#pragma unroll
    for (int m = 0; m < 4; ++m)
      a[m] = *(const short8*)&Alds[(wr + m * 16 + lrow) * BK + lk];
#pragma unroll
    for (int n = 0; n < 2; ++n)
      b[n] = *(const short8*)&Blds[(wc + n * 16 + lrow) * BK + lk];
#pragma unroll
    for (int m = 0; m < 4; ++m)
#pragma unroll
      for (int n = 0; n < 2; ++n)
        acc[m][n] = __builtin_amdgcn_mfma_f32_16x16x32_bf16(a[m], b[n], acc[m][n], 0, 0, 0);
    __syncthreads();
  }

  float asv[2], adv[2];
#pragma unroll
  for (int n = 0; n < 2; ++n) {
    asv[n] = as2[wc + n * 16 + lrow];
    adv[n] = ad2[wc + n * 16 + lrow];
  }
#pragma unroll
  for (int m = 0; m < 4; ++m) {
#pragma unroll
    for (int j = 0; j < 4; ++j) {
      int rl = wr + m * 16 + (lane >> 4) * 4 + j;
      int r = row0 + rl;
      float ps = 0.f, pd = 0.f;
#pragma unroll
      for (int n = 0; n < 2; ++n) {
        float v = acc[m][n][j];
        ps += v * asv[n];
        pd += v * adv[n];
        if (r < M) Cb[(size_t)r * Nn + wc + n * 16 + lrow] = f2bf(v);
      }
#pragma unroll
      for (int s = 1; s < 16; s <<= 1) {
        ps += __shfl_xor(ps, s);
        pd += __shfl_xor(pd, s);
      }
      if ((lane & 15) == 0) {
        atomicAdd(&sps[rl], ps);
        atomicAdd(&spd[rl], pd);
      }
    }
  }
  __syncthreads();
  if (t < BM) {
    int r = row0 + t;
    if (r < M) { als[r] = sps[t]; ald[r] = spd[t]; }
  }
}

// ---------------- aggregation (unchanged from R5: at ~3 TB/s gather wall) ------------

__global__ void agg1_kernel(const unsigned short* __restrict__ h1b,
                            const float4* __restrict__ als1, const float4* __restrict__ ald1,
                            const int* __restrict__ rowoff, const int* __restrict__ esrc,
                            const float* __restrict__ b1, unsigned short* __restrict__ hact,
                            int n) {
  __shared__ float wlds[4][256];
  __shared__ int   slds[4][64];
  int w = threadIdx.x >> 6;
  int node = blockIdx.x * 4 + w;
  if (node >= n) return;
  int lane = threadIdx.x & 63;
  int hi = lane >> 5;
  int cl = lane & 31;
  int head = cl >> 3;
  int beg = rowoff[node], end = rowoff[node + 1];
  float4 aldn = ald1[node];
  f32x4 accA = {0.f, 0.f, 0.f, 0.f};
  f32x4 accB = {0.f, 0.f, 0.f, 0.f};
  float dl0 = 0.f, dl1 = 0.f, dl2 = 0.f, dl3 = 0.f;

  for (int base = beg; base < end; base += 64) {
    int cnt = min(64, end - base);
    if (lane < cnt) {
      int s = esrc[base + lane];
      float4 av = als1[s];
      float v, w0, w1, w2, w3;
      v = av.x + aldn.x; v = fmaxf(v, NEG_SLOPE * v); w0 = __expf(v);
      v = av.y + aldn.y; v = fmaxf(v, NEG_SLOPE * v); w1 = __expf(v);
      v = av.z + aldn.z; v = fmaxf(v, NEG_SLOPE * v); w2 = __expf(v);
      v = av.w + aldn.w; v = fmaxf(v, NEG_SLOPE * v); w3 = __expf(v);
      dl0 += w0; dl1 += w1; dl2 += w2; dl3 += w3;
      slds[w][lane] = s;
      float4 wv = {w0, w1, w2, w3};
      *(float4*)&wlds[w][lane * 4] = wv;
    }

    uint4 dA[4], dB[4];
    float wA[4], wB[4];
    auto ISSUE = [&](int j0, uint4* d, float* wj) {
#pragma unroll
      for (int ii = 0; ii < 4; ++ii) {
        int e = j0 + 2 * ii + hi;
        bool val = e < cnt;
        int se = val ? e : 0;
        int ss = slds[w][se];
        wj[ii] = val ? wlds[w][se * 4 + head] : 0.f;
        d[ii] = *(const uint4*)&h1b[(size_t)ss * HC1 + cl * 8];
      }
    };
    auto CONSUME = [&](const uint4* d, const float* wj) {
#pragma unroll
      for (int ii = 0; ii < 4; ++ii) {
        float q = wj[ii];
        accA[0] += q * bflo(d[ii].x); accA[1] += q * bfhi(d[ii].x);
        accA[2] += q * bflo(d[ii].y); accA[3] += q * bfhi(d[ii].y);
        accB[0] += q * bflo(d[ii].z); accB[1] += q * bfhi(d[ii].z);
        accB[2] += q * bflo(d[ii].w); accB[3] += q * bfhi(d[ii].w);
      }
    };

    ISSUE(0, dA, wA);
    for (int j0 = 8;; j0 += 16) {
      bool hasB = j0 < cnt;
      if (hasB) ISSUE(j0, dB, wB);
      CONSUME(dA, wA);
      if (!hasB) break;
      bool hasA = (j0 + 8) < cnt;
      if (hasA) ISSUE(j0 + 8, dA, wA);
      CONSUME(dB, wB);
      if (!hasA) break;
    }
  }

#pragma unroll
  for (int k = 0; k < 4; ++k) {
    accA[k] += __shfl_xor(accA[k], 32);
    accB[k] += __shfl_xor(accB[k], 32);
  }
  float d0 = wave_sum(dl0), d1 = wave_sum(dl1);
  float d2 = wave_sum(dl2), d3 = wave_sum(dl3);
  float den = head < 2 ? (head == 0 ? d0 : d1) : (head == 2 ? d2 : d3);
  float rden = 1.f / (den + EPS_DENOM);
  if (hi == 0) {
    float4 bv0 = *(const float4*)&b1[cl * 8];
    float4 bv1 = *(const float4*)&b1[cl * 8 + 4];
    float o[8];
    o[0] = accA[0] * rden + bv0.x; o[1] = accA[1] * rden + bv0.y;
    o[2] = accA[2] * rden + bv0.z; o[3] = accA[3] * rden + bv0.w;
    o[4] = accB[0] * rden + bv1.x; o[5] = accB[1] * rden + bv1.y;
    o[6] = accB[2] * rden + bv1.z; o[7] = accB[3] * rden + bv1.w;
    ushort4 ov0, ov1;
#pragma unroll
    for (int k = 0; k < 8; ++k) o[k] = o[k] > 0.f ? o[k] : __expf(o[k]) - 1.f;  // ELU
    ov0.x = f2bf(o[0]); ov0.y = f2bf(o[1]); ov0.z = f2bf(o[2]); ov0.w = f2bf(o[3]);
    ov1.x = f2bf(o[4]); ov1.y = f2bf(o[5]); ov1.z = f2bf(o[6]); ov1.w = f2bf(o[7]);
    *(ushort4*)&hact[(size_t)node * HC1 + cl * 8] = ov0;
    *(ushort4*)&hact[(size_t)node * HC1 + cl * 8 + 4] = ov1;
  }
}

__global__ void agg2_kernel(const unsigned short* __restrict__ h2b,
                            const float* __restrict__ als2, const float* __restrict__ ald2,
                            const int* __restrict__ rowoff, const int* __restrict__ esrc,
                            const float* __restrict__ b2, float* __restrict__ out, int n) {
  __shared__ float wlds[4][64];
  __shared__ int   slds[4][64];
  int w = threadIdx.x >> 6;
  int node = blockIdx.x * 4 + w;
  if (node >= n) return;
  int lane = threadIdx.x & 63;
  int eg = lane >> 3;
  int cl = lane & 7;
  int beg = rowoff[node], end = rowoff[node + 1];
  float aldn = ald2[node];
  f32x4 accA = {0.f, 0.f, 0.f, 0.f};
  f32x4 accB = {0.f, 0.f, 0.f, 0.f};
  float dl = 0.f;
  for (int base = beg; base < end; base += 64) {
    int cnt = min(64, end - base);
    if (lane < cnt) {
      int s = esrc[base + lane];
      float v = als2[s] + aldn;
      v = fmaxf(v, NEG_SLOPE * v);
      float wl = __expf(v);
      dl += wl;
      slds[w][lane] = s;
      wlds[w][lane] = wl;
    }
    for (int j0 = 0; j0 < cnt; j0 += 32) {
      uint4 d[4]; float wj[4];
#pragma unroll
      for (int ii = 0; ii < 4; ++ii) {
        int e = j0 + ii * 8 + eg;
        bool val = e < cnt;
        int se = val ? e : 0;
        int ss = slds[w][se];
        wj[ii] = val ? wlds[w][se] : 0.f;
        d[ii] = *(const uint4*)&h2b[(size_t)ss * NCLS + cl * 8];
      }
#pragma unroll
      for (int ii = 0; ii < 4; ++ii) {
        float q = wj[ii];
        accA[0] += q * bflo(d[ii].x); accA[1] += q * bfhi(d[ii].x);
        accA[2] += q * bflo(d[ii].y); accA[3] += q * bfhi(d[ii].y);
        accB[0] += q * bflo(d[ii].z); accB[1] += q * bfhi(d[ii].z);
        accB[2] += q * bflo(d[ii].w); accB[3] += q * bfhi(d[ii].w);
      }
    }
  }
#pragma unroll
  for (int s = 8; s < 64; s <<= 1) {
#pragma unroll
    for (int k = 0; k < 4; ++k) {
      accA[k] += __shfl_xor(accA[k], s);
      accB[k] += __shfl_xor(accB[k], s);
    }
  }
  float den = wave_sum(dl);
  float rden = 1.f / (den + EPS_DENOM);
  float4 bv0 = *(const float4*)&b2[cl * 8];
  float4 bv1 = *(const float4*)&b2[cl * 8 + 4];
  float o[8];
  o[0] = accA[0] * rden + bv0.x; o[1] = accA[1] * rden + bv0.y;
  o[2] = accA[2] * rden + bv0.z; o[3] = accA[3] * rden + bv0.w;
  o[4] = accB[0] * rden + bv1.x; o[5] = accB[1] * rden + bv1.y;
  o[6] = accB[2] * rden + bv1.z; o[7] = accB[3] * rden + bv1.w;
  float mx = o[0];
#pragma unroll
  for (int k = 1; k < 8; ++k) mx = fmaxf(mx, o[k]);
#pragma unroll
  for (int s = 1; s < 8; s <<= 1) mx = fmaxf(mx, __shfl_xor(mx, s));
  float sm = 0.f;
#pragma unroll
  for (int k = 0; k < 8; ++k) sm += __expf(o[k] - mx);
#pragma unroll
  for (int s = 1; s < 8; s <<= 1) sm += __shfl_xor(sm, s);
  float ls = mx + __logf(sm);
  if (lane < 8) {
    float4 q0 = {o[0] - ls, o[1] - ls, o[2] - ls, o[3] - ls};
    float4 q1 = {o[4] - ls, o[5] - ls, o[6] - ls, o[7] - ls};
    *(float4*)&out[(size_t)node * NCLS + cl * 8] = q0;
    *(float4*)&out[(size_t)node * NCLS + cl * 8 + 4] = q1;
  }
}

// ---------------- launch ----------------

extern "C" void kernel_launch(void* const* d_in, const int* in_sizes, int n_in,
                              void* d_out, int out_size, void* d_ws, size_t ws_size,
                              hipStream_t stream) {
  const float* x      = (const float*)d_in[0];
  const int*   eidx   = (const int*)d_in[1];
  const float* W1     = (const float*)d_in[2];
  const float* a_src1 = (const float*)d_in[3];
  const float* a_dst1 = (const float*)d_in[4];
  const float* b1     = (const float*)d_in[5];
  const float* W2     = (const float*)d_in[6];
  const float* a_src2 = (const float*)d_in[7];
  const float* a_dst2 = (const float*)d_in[8];
  const float* b2     = (const float*)d_in[9];
  float* out = (float*)d_out;

  const int Nn = in_sizes[0] / F_IN;   // 50000
  const int E  = in_sizes[1] / 2;      // 800000
  const int* esrc_in = eidx;
  const int* edst_in = eidx + E;

  char* ws = (char*)d_ws;
  size_t off = 0;
  auto alloc = [&](size_t bytes) -> void* {
    void* p = ws + off;
    off += (bytes + 255) & ~(size_t)255;
    return p;
  };
  unsigned short* h1b    = (unsigned short*)alloc((size_t)Nn * HC1 * sizeof(short));
  unsigned short* hact   = (unsigned short*)alloc((size_t)Nn * HC1 * sizeof(short));
  unsigned short* h2b    = (unsigned short*)alloc((size_t)Nn * NCLS * sizeof(short));
  unsigned short* W1T    = (unsigned short*)alloc((size_t)F_IN * HC1 * sizeof(short));
  unsigned short* W2T    = (unsigned short*)alloc((size_t)HC1 * NCLS * sizeof(short));
  float*          als1   = (float*)alloc((size_t)Nn * HEADS * sizeof(float));
  float*          ald1   = (float*)alloc((size_t)Nn * HEADS * sizeof(float));
  float*          als2   = (float*)alloc((size_t)Nn * sizeof(float));
  float*          ald2   = (float*)alloc((size_t)Nn * sizeof(float));
  int*            cnt    = (int*)alloc((size_t)Nn * sizeof(int));
  int*            rowoff = (int*)alloc((size_t)(Nn + 1) * sizeof(int));
  int*            cursor = (int*)alloc((size_t)Nn * sizeof(int));
  int*            bsum   = (int*)alloc(256 * sizeof(int));
  int*            esrc   = (int*)alloc((size_t)(E + Nn) * sizeof(int));

  const int nscan = (Nn + 1023) / 1024;

  castT_kernel<<<(F_IN * HC1 + 255) / 256, 256, 0, stream>>>(W1, W1T, F_IN, HC1);
  castT_kernel<<<(HC1 * NCLS + 255) / 256, 256, 0, stream>>>(W2, W2T, HC1, NCLS);

  hipMemsetAsync(cnt, 0, (size_t)Nn * sizeof(int), stream);
  hist_kernel<<<(E + 255) / 256, 256, 0, stream>>>(edst_in, E, cnt);
  scan_blocks_kernel<<<nscan, 1024, 0, stream>>>(cnt, Nn, rowoff, cursor, bsum);
  scan_partials_kernel<<<1, 64, 0, stream>>>(bsum, nscan);
  scan_add_kernel<<<nscan, 1024, 0, stream>>>(Nn, rowoff, cursor, bsum);
  scatter_kernel<<<(E + Nn + 255) / 256, 256, 0, stream>>>(esrc_in, edst_in, E, Nn, cursor, esrc);

  // layer 1: GEMM + fused attn1 logits
  {
    int blocks = (Nn + 127) / 128;
    gemm1_fused_kernel<<<blocks, 512, 0, stream>>>(x, W1T, h1b, a_src1, a_dst1,
                                                   als1, ald1, Nn);
    int ablocks = (Nn + 3) / 4;
    agg1_kernel<<<ablocks, 256, 0, stream>>>(h1b, (const float4*)als1, (const float4*)ald1,
                                             rowoff, esrc, b1, hact, Nn);
  }

  // layer 2: GEMM + fused attn2 logits
  {
    int blocks = (Nn + 127) / 128;
    gemm2_fused_kernel<<<blocks, 256, 0, stream>>>(hact, W2T, h2b, a_src2, a_dst2,
                                                   als2, ald2, Nn);
    int ablocks = (Nn + 3) / 4;
    agg2_kernel<<<ablocks, 256, 0, stream>>>(h2b, als2, ald2, rowoff, esrc, b2, out, Nn);
  }
}